// Round 1
// 639.781 us; speedup vs baseline: 1.0259x; 1.0259x over previous
//
#include <hip/hip_runtime.h>
#include <math.h>

// ---------------------------------------------------------------------------
// HybridGNN on MI355X — R4.
// agg v3: removed the 44.8KB per-block LDS W staging (it capped occupancy at
//         2 blocks/CU). Phase C now reads W directly from global (L1/L2-
//         resident, wave-broadcast addresses) as 2x float2 (8B-aligned for
//         the [100][50] row stride). LDS 72KB -> 27.4KB => 5 blocks/CU,
//         __launch_bounds__(256,5) keeps VGPRs under the 5-wave/EU cap.
//         Theory: launch 0 is latency-bound (Occ 21%, HBM 21%, VALU 23%);
//         2.5-3x occupancy overlaps gather/compute phases across blocks.
// attn:  unchanged from R3.
// Workspace layout identical to R1 (rows of 100 f32).
// ---------------------------------------------------------------------------

#define NBATCH 512
#define TOTALP 1086
#define RPB 32      // rows per agg block (all segment row counts divide by 32)
#define XSTR 204    // xs LDS row stride (floats), breaks 800-stride bank alias

struct Seg {
  const float* emb;     // gather mode embedding base (null => dense mode)
  const float* selfp;   // dense self rows [N][100]
  const float* neighp;  // dense neighbor rows [N*r][100]
  const int*   ids_s;   // gather: self id array
  const int*   ids_n;   // gather: neighbor id array
  const float* Ws;      // [100][50]
  const float* Wn;      // [100][50]
  float*       outp;    // out row j at outp + j*ostride
  int ss, so;           // self id per-b stride, offset
  int ns, no;           // neigh id per-b stride, offset
  int estride;          // node stride in emb (elements)
  int ostride;
  int c;                // self rows per batch element
  int r;                // fanout
  int blk_begin;        // prefix in fused BLOCK space
};

struct KArgs { Seg seg[14]; int n; };

__global__ __launch_bounds__(256, 5) void agg_kernel(KArgs P) {
  __shared__ float xsh[RPB * XSTR];     // 26.1 KB  xs[row][0:100]=s, [100:200]=m
  __shared__ int   ids_s_sh[RPB];
  __shared__ int   ids_n_sh[RPB * 9];

  const int blk = blockIdx.x, tid = threadIdx.x;
  int si = 0;
  for (int i = 1; i < P.n; ++i)
    if (blk >= P.seg[i].blk_begin) si = i;
  const Seg sg = P.seg[si];
  const int j0 = (blk - sg.blk_begin) * RPB;
  const int c = sg.c, r = sg.r;

  // ---- ids staging (gather mode) ----
  if (sg.emb) {
    if (tid < RPB) {
      int j = j0 + tid, b = j / c, pos = j - b * c;
      ids_s_sh[tid] = sg.ids_s[(long)b * sg.ss + sg.so + pos];
    }
    for (int u = tid; u < RPB * r; u += 256) {
      int row = u / r, q = u - row * r;
      int j = j0 + row, b = j / c, pos = j - b * c;
      ids_n_sh[u] = sg.ids_n[(long)b * sg.ns + sg.no + pos * r + q];
    }
  }
  __syncthreads();

  // ---- Phase B: gather/load X into LDS ----
  const float rinv = 1.f / (float)r;
  for (int u = tid; u < RPB * 25; u += 256) {
    int row = u / 25, q4 = (u - row * 25) * 4;
    float sx, sy, sz, sw, mx = 0.f, my = 0.f, mz = 0.f, mw = 0.f;
    if (sg.emb) {
      const float4 s4 = *(const float4*)(sg.emb + (long)ids_s_sh[row] * sg.estride + q4);
      sx = s4.x; sy = s4.y; sz = s4.z; sw = s4.w;
      for (int rr = 0; rr < r; ++rr) {
        const float4 t = *(const float4*)(sg.emb + (long)ids_n_sh[row * r + rr] * sg.estride + q4);
        mx += t.x; my += t.y; mz += t.z; mw += t.w;
      }
    } else {
      long j = j0 + row;
      const float4 s4 = *(const float4*)(sg.selfp + j * 100 + q4);
      sx = s4.x; sy = s4.y; sz = s4.z; sw = s4.w;
      for (int rr = 0; rr < r; ++rr) {
        const float4 t = *(const float4*)(sg.neighp + (j * r + rr) * 100 + q4);
        mx += t.x; my += t.y; mz += t.z; mw += t.w;
      }
    }
    float4 sv; sv.x = sx; sv.y = sy; sv.z = sz; sv.w = sw;
    float4 mv; mv.x = mx * rinv; mv.y = my * rinv; mv.z = mz * rinv; mv.w = mw * rinv;
    *(float4*)&xsh[row * XSTR + q4]       = sv;
    *(float4*)&xsh[row * XSTR + 100 + q4] = mv;
  }
  __syncthreads();

  // ---- Phase C: 4 rows x 4 cols register-tiled matvec, W from global ----
  // Thread (rg, cq): rows rg*4..rg*4+3, half = (cq<14 ? self : neigh),
  // cols 4*cl..4*cl+3 of that half (cl = cq%14; cl==13 is a pad thread,
  // cl==12 has only 2 valid cols). W rows are 50 floats (8B-aligned at any
  // even col), so load two float2; the second address is clamped for cl>=12
  // so no access ever goes past the 100x50 weight block.
  if (tid < 224) {
    const int rg = tid / 28, cq = tid - rg * 28;
    const int cl = (cq < 14) ? cq : cq - 14;
    const float* Wg = (cq < 14) ? sg.Ws : sg.Wn;
    const int c0 = (cl < 13) ? 4 * cl : 0;
    const int c1 = (cl < 12) ? c0 + 2 : c0;
    const int xoff = (cq < 14) ? 0 : 100;
    float acc[4][4];
#pragma unroll
    for (int i = 0; i < 4; ++i) { acc[i][0] = acc[i][1] = acc[i][2] = acc[i][3] = 0.f; }
    const float* xb = &xsh[(rg * 4) * XSTR + xoff];
#pragma unroll 4
    for (int e = 0; e < 100; ++e) {
      const float2 w0 = *(const float2*)&Wg[e * 50 + c0];
      const float2 w1 = *(const float2*)&Wg[e * 50 + c1];
#pragma unroll
      for (int i = 0; i < 4; ++i) {
        const float a = xb[i * XSTR + e];
        acc[i][0] = fmaf(a, w0.x, acc[i][0]);
        acc[i][1] = fmaf(a, w0.y, acc[i][1]);
        acc[i][2] = fmaf(a, w1.x, acc[i][2]);
        acc[i][3] = fmaf(a, w1.y, acc[i][3]);
      }
    }
    if (cl < 13) {
      const int cbase = (cq < 14 ? 0 : 50) + 4 * cl;
      for (int i = 0; i < 4; ++i) {
        const long j = j0 + rg * 4 + i;
        float* op = sg.outp + j * (long)sg.ostride + cbase;
        if (cl < 12) {
          float4 o;
          o.x = fmaxf(acc[i][0], 0.f); o.y = fmaxf(acc[i][1], 0.f);
          o.z = fmaxf(acc[i][2], 0.f); o.w = fmaxf(acc[i][3], 0.f);
          *(float4*)op = o;
        } else {   // cols 48,49 (or 98,99)
          op[0] = fmaxf(acc[i][0], 0.f);
          op[1] = fmaxf(acc[i][1], 0.f);
        }
      }
    }
  }
}

// ---------------------------------------------------------------------------
// Attention step, W staged through LDS chunks.  x rows at xs[base+i*rs+d].
// ---------------------------------------------------------------------------
__device__ __forceinline__ void attn_step(
    float* xs, int base, int rs, int n,
    const float* Wq, const float* Wk, const float* Wv, const float* Wf,
    const float* g, const float* bb,
    float* ln, float* qq, float* kk, float* vv, float* ot,
    float* sc, float* musd, float* wsh, int tid)
{
  if (tid < n) {
    float mu = 0.f;
    for (int d = 0; d < 100; ++d) mu += xs[base + tid * rs + d];
    mu *= 0.01f;
    float var = 0.f;
    for (int d = 0; d < 100; ++d) {
      float t = xs[base + tid * rs + d] - mu; var = fmaf(t, t, var);
    }
    var *= 0.01f;
    musd[tid * 2]     = mu;
    musd[tid * 2 + 1] = rsqrtf(var + 1e-6f);
  }
  __syncthreads();
  for (int o = tid; o < n * 100; o += 128) {
    int i = o / 100, d = o - i * 100;
    ln[o] = (xs[base + i * rs + d] - musd[i * 2]) * musd[i * 2 + 1] * g[d] + bb[d];
  }
  __syncthreads();

  // ---- q,k,v: thread owns (row i, 4 cols d4), W chunks of 50 e-rows ----
  const bool act = tid < n * 25;
  const int  i   = tid / 25;
  const int  d4  = 4 * (tid - i * 25);
  float aq[4] = {0,0,0,0}, ak[4] = {0,0,0,0}, av[4] = {0,0,0,0};
  for (int ch = 0; ch < 2; ++ch) {
    for (int u = tid; u < 1250; u += 128) {
      int el = u / 25, dd = 4 * (u - el * 25);
      *(float4*)&wsh[el * 300 + dd]       = *(const float4*)&Wq[(ch * 50 + el) * 100 + dd];
      *(float4*)&wsh[el * 300 + 100 + dd] = *(const float4*)&Wk[(ch * 50 + el) * 100 + dd];
      *(float4*)&wsh[el * 300 + 200 + dd] = *(const float4*)&Wv[(ch * 50 + el) * 100 + dd];
    }
    __syncthreads();
    if (act) {
      for (int el = 0; el < 50; ++el) {
        const float lnv = ln[i * 100 + ch * 50 + el];
        const float xv  = xs[base + i * rs + ch * 50 + el];
        const float4 wq = *(const float4*)&wsh[el * 300 + d4];
        const float4 wk = *(const float4*)&wsh[el * 300 + 100 + d4];
        const float4 wv = *(const float4*)&wsh[el * 300 + 200 + d4];
        aq[0] = fmaf(lnv, wq.x, aq[0]); aq[1] = fmaf(lnv, wq.y, aq[1]);
        aq[2] = fmaf(lnv, wq.z, aq[2]); aq[3] = fmaf(lnv, wq.w, aq[3]);
        ak[0] = fmaf(xv,  wk.x, ak[0]); ak[1] = fmaf(xv,  wk.y, ak[1]);
        ak[2] = fmaf(xv,  wk.z, ak[2]); ak[3] = fmaf(xv,  wk.w, ak[3]);
        av[0] = fmaf(xv,  wv.x, av[0]); av[1] = fmaf(xv,  wv.y, av[1]);
        av[2] = fmaf(xv,  wv.z, av[2]); av[3] = fmaf(xv,  wv.w, av[3]);
      }
    }
    __syncthreads();
  }
  if (act) {
#pragma unroll
    for (int jj = 0; jj < 4; ++jj) {
      qq[i * 100 + d4 + jj] = aq[jj];
      kk[i * 100 + d4 + jj] = ak[jj];
      vv[i * 100 + d4 + jj] = av[jj];
    }
  }
  __syncthreads();

  if (tid < n * n) {
    int qi = tid / n, u = tid - qi * n;
    float s = 0.f;
    for (int d = 0; d < 100; ++d) s = fmaf(qq[qi * 100 + d], kk[u * 100 + d], s);
    sc[tid] = s * 0.1f;
  }
  __syncthreads();
  if (tid < n) {
    float mx = sc[tid * n];
    for (int u = 1; u < n; ++u) mx = fmaxf(mx, sc[tid * n + u]);
    float sm = 0.f;
    for (int u = 0; u < n; ++u) {
      float e = expf(sc[tid * n + u] - mx); sc[tid * n + u] = e; sm += e;
    }
    float inv = 1.f / sm;
    for (int u = 0; u < n; ++u) sc[tid * n + u] *= inv;
  }
  __syncthreads();
  for (int o = tid; o < n * 100; o += 128) {
    int ii = o / 100, d = o - ii * 100;
    float a = 0.f;
    for (int u = 0; u < n; ++u) a = fmaf(sc[ii * n + u], vv[u * 100 + d], a);
    ot[o] = a;
  }
  __syncthreads();

  // ---- Wf + residual, chunked through LDS ----
  float af[4] = {0,0,0,0};
  for (int ch = 0; ch < 2; ++ch) {
    for (int u = tid; u < 1250; u += 128) {
      int el = u / 25, dd = 4 * (u - el * 25);
      *(float4*)&wsh[el * 100 + dd] = *(const float4*)&Wf[(ch * 50 + el) * 100 + dd];
    }
    __syncthreads();
    if (act) {
      for (int el = 0; el < 50; ++el) {
        const float ov = ot[i * 100 + ch * 50 + el];
        const float4 wf = *(const float4*)&wsh[el * 100 + d4];
        af[0] = fmaf(ov, wf.x, af[0]); af[1] = fmaf(ov, wf.y, af[1]);
        af[2] = fmaf(ov, wf.z, af[2]); af[3] = fmaf(ov, wf.w, af[3]);
      }
    }
    __syncthreads();
  }
  if (act) {
#pragma unroll
    for (int jj = 0; jj < 4; ++jj)
      xs[base + i * rs + d4 + jj] += af[jj];
  }
  __syncthreads();
}

__global__ __launch_bounds__(128) void attn_final_kernel(
    const float* __restrict__ spec, const float* __restrict__ rview,
    const int* __restrict__ nodeids, const int* __restrict__ edgetype,
    const float* __restrict__ base_embed, const float* __restrict__ reflect,
    const float* vWq, const float* vWk, const float* vWv, const float* vWf,
    const float* vg, const float* vb,
    const float* mWq, const float* mWk, const float* mWv, const float* mWf,
    const float* mg, const float* mb,
    float* __restrict__ out)
{
  __shared__ float xs[600], ln[300], qq[300], kk[300], vv[300], ot[300];
  __shared__ float sc[9], musd[6], r200[200], pooled[200], nrmv[1];
  __shared__ float wsh[15000];
  const int b = blockIdx.x, tid = threadIdx.x;

  for (int o = tid; o < 600; o += 128) {
    int v = o / 200, rem = o - v * 200;
    xs[o] = (v < 2) ? spec[(long)b * 400 + o] : rview[(long)b * 100 + (rem % 100)];
  }
  __syncthreads();

  for (int v = 0; v < 3; ++v)
    attn_step(xs, v * 200, 100, 2, vWq, vWk, vWv, vWf, vg, vb,
              ln, qq, kk, vv, ot, sc, musd, wsh, tid);
  for (int t = 0; t < 2; ++t)
    attn_step(xs, t * 100, 200, 3, mWq, mWk, mWv, mWf, mg, mb,
              ln, qq, kk, vv, ot, sc, musd, wsh, tid);

  for (int o = tid; o < 200; o += 128)
    pooled[o] = (xs[o] + xs[200 + o] + xs[400 + o]) * (1.f / 3.f);
  __syncthreads();

  const int  et  = edgetype[NBATCH + b];
  const long nid = nodeids[b];

  float ar[4] = {0,0,0,0};
  if (tid < 50) {
    const float4 be = *(const float4*)&base_embed[nid * 200 + 4 * tid];
    ar[0] = be.x; ar[1] = be.y; ar[2] = be.z; ar[3] = be.w;
  }
  for (int ch = 0; ch < 2; ++ch) {
    for (int u = tid; u < 2500; u += 128) {
      int dl = u / 50, oo = 4 * (u - dl * 50);
      *(float4*)&wsh[dl * 200 + oo] =
          *(const float4*)&reflect[((long)et * 100 + ch * 50 + dl) * 200 + oo];
    }
    __syncthreads();
    if (tid < 50) {
      for (int dl = 0; dl < 50; ++dl) {
        const float pv = pooled[et * 100 + ch * 50 + dl];
        const float4 rv = *(const float4*)&wsh[dl * 200 + 4 * tid];
        ar[0] = fmaf(pv, rv.x, ar[0]); ar[1] = fmaf(pv, rv.y, ar[1]);
        ar[2] = fmaf(pv, rv.z, ar[2]); ar[3] = fmaf(pv, rv.w, ar[3]);
      }
    }
    __syncthreads();
  }
  if (tid < 50) {
    r200[4 * tid]     = ar[0]; r200[4 * tid + 1] = ar[1];
    r200[4 * tid + 2] = ar[2]; r200[4 * tid + 3] = ar[3];
  }
  __syncthreads();
  if (tid == 0) {
    float ss = 0.f;
    for (int o = 0; o < 200; ++o) ss = fmaf(r200[o], r200[o], ss);
    nrmv[0] = 1.f / fmaxf(sqrtf(ss), 1e-12f);
  }
  __syncthreads();
  for (int o = tid; o < 200; o += 128)
    out[(long)b * 200 + o] = r200[o] * nrmv[0];
}

// ---------------------------------------------------------------------------
extern "C" void kernel_launch(void* const* d_in, const int* in_sizes, int n_in,
                              void* d_out, int out_size, void* d_ws, size_t ws_size,
                              hipStream_t stream) {
  (void)in_sizes; (void)n_in; (void)out_size; (void)ws_size;
  const int*   nodeids          = (const int*)d_in[0];
  const int*   edgetype         = (const int*)d_in[1];
  const int*   neighbors        = (const int*)d_in[2];
  const int*   random_neighbors = (const int*)d_in[3];
  const float* base_embed       = (const float*)d_in[4];
  const float* type_embed       = (const float*)d_in[5];
  const float* rw_embed         = (const float*)d_in[6];
  const float* reflect          = (const float*)d_in[7];
  const float* agg0_self        = (const float*)d_in[8];
  const float* agg0_neigh       = (const float*)d_in[9];
  const float* agg1_self        = (const float*)d_in[10];
  const float* agg1_neigh       = (const float*)d_in[11];
  const float* rand_self        = (const float*)d_in[12];
  const float* rand_neigh       = (const float*)d_in[13];
  const float* vWq = (const float*)d_in[14];
  const float* vWk = (const float*)d_in[15];
  const float* vWv = (const float*)d_in[16];
  const float* vWf = (const float*)d_in[17];
  const float* vg  = (const float*)d_in[18];
  const float* vb  = (const float*)d_in[19];
  const float* mWq = (const float*)d_in[20];
  const float* mWk = (const float*)d_in[21];
  const float* mWv = (const float*)d_in[22];
  const float* mWf = (const float*)d_in[23];
  const float* mg  = (const float*)d_in[24];
  const float* mb  = (const float*)d_in[25];

  float* ws = (float*)d_ws;
  const long S1r = 147L * NBATCH;                 // schema1 rows per t
  auto rp = [&](long rows) { return ws + rows * 100; };
  float* spec_f  = ws + 306L * NBATCH * 100;      // [B][2][2][100]
  float* rview_f = spec_f + (long)NBATCH * 400;   // [B][100]

  const int  OFF1[4] = {18, 21, 36, 141};
  const int  FAN1[4] = {3, 5, 7, 9};
  const int  C1[4]   = {1, 3, 15, 105};
  const long CUM1[4]  = {0, 1, 4, 19};
  const long CUM1b[3] = {0, 1, 4};

  KArgs A; long acc = 0;   // acc in BLOCKS (32 rows each)
  auto addg = [&](const float* emb, int estride,
                  const int* isrc, int ss, int so, int c,
                  const int* insrc, int nstr, int no, int r,
                  const float* Ws, const float* Wn, float* outp, int ostride) {
    Seg& s = A.seg[A.n++];
    s.emb = emb; s.selfp = nullptr; s.neighp = nullptr;
    s.ids_s = isrc; s.ids_n = insrc;
    s.Ws = Ws; s.Wn = Wn; s.outp = outp;
    s.ss = ss; s.so = so; s.ns = nstr; s.no = no;
    s.estride = estride; s.ostride = ostride;
    s.c = c; s.r = r; s.blk_begin = (int)acc;
    acc += (long)c * NBATCH / RPB;
  };
  auto addd = [&](const float* selfp, const float* neighp, int c, int r,
                  const float* Ws, const float* Wn, float* outp, int ostride) {
    Seg& s = A.seg[A.n++];
    s.emb = nullptr; s.selfp = selfp; s.neighp = neighp;
    s.ids_s = nullptr; s.ids_n = nullptr;
    s.Ws = Ws; s.Wn = Wn; s.outp = outp;
    s.ss = 0; s.so = 0; s.ns = 0; s.no = 0; s.estride = 0; s.ostride = ostride;
    s.c = c; s.r = r; s.blk_begin = (int)acc;
    acc += (long)c * NBATCH / RPB;
  };

  // ---- launch 0: all level-0 (gather) pairs ----
  A.n = 0; acc = 0;
  for (int t = 0; t < 2; ++t)
    for (int k = 0; k < 4; ++k) {
      const float* emb = type_embed + (t * 2 + 1) * 100;
      if (k == 0)
        addg(emb, 400, nodeids, 1, 0, 1,
             neighbors, 2 * TOTALP, t * TOTALP + OFF1[k], FAN1[k],
             agg1_self, agg1_neigh, rp(t * S1r + CUM1[k] * NBATCH), 100);
      else
        addg(emb, 400, neighbors, 2 * TOTALP, t * TOTALP + OFF1[k - 1], C1[k],
             neighbors, 2 * TOTALP, t * TOTALP + OFF1[k], FAN1[k],
             agg1_self, agg1_neigh, rp(t * S1r + CUM1[k] * NBATCH), 100);
    }
  for (int t = 0; t < 2; ++t)
    for (int k = 0; k < 2; ++k) {
      const float* emb = type_embed + (t * 2 + 0) * 100;
      long obase = 294L * NBATCH + (long)t * 4 * NBATCH + (k == 0 ? 0 : 1) * NBATCH;
      if (k == 0)
        addg(emb, 400, nodeids, 1, 0, 1,
             neighbors, 2 * TOTALP, t * TOTALP + 0, 3,
             agg0_self, agg0_neigh, rp(obase), 100);
      else
        addg(emb, 400, neighbors, 2 * TOTALP, t * TOTALP + 0, 3,
             neighbors, 2 * TOTALP, t * TOTALP + 3, 5,
             agg0_self, agg0_neigh, rp(obase), 100);
    }
  for (int k = 0; k < 2; ++k) {
    long obase = 302L * NBATCH + (k == 0 ? 0 : 1) * NBATCH;
    if (k == 0)
      addg(rw_embed, 100, nodeids, 1, 0, 1,
           random_neighbors, 18, 0, 3, rand_self, rand_neigh, rp(obase), 100);
    else
      addg(rw_embed, 100, random_neighbors, 18, 0, 3,
           random_neighbors, 18, 3, 5, rand_self, rand_neigh, rp(obase), 100);
  }
  agg_kernel<<<dim3((unsigned)acc), dim3(256), 0, stream>>>(A);

  // ---- launch 1: schema1 L1, schema0 L1 (final), random L1 (final) ----
  A.n = 0; acc = 0;
  for (int t = 0; t < 2; ++t)
    for (int k = 0; k < 3; ++k)
      addd(rp(t * S1r + CUM1[k] * NBATCH), rp(t * S1r + CUM1[k + 1] * NBATCH),
           C1[k], FAN1[k], agg1_self + 5000, agg1_neigh + 5000,
           rp(t * S1r + 124L * NBATCH + CUM1b[k] * NBATCH), 100);
  for (int t = 0; t < 2; ++t)
    addd(rp(294L * NBATCH + (long)t * 4 * NBATCH),
         rp(294L * NBATCH + (long)t * 4 * NBATCH + NBATCH),
         1, 3, agg0_self + 5000, agg0_neigh + 5000, spec_f + t * 100, 400);
  addd(rp(302L * NBATCH), rp(303L * NBATCH), 1, 3,
       rand_self + 5000, rand_neigh + 5000, rview_f, 100);
  agg_kernel<<<dim3((unsigned)acc), dim3(256), 0, stream>>>(A);

  // ---- launch 2: schema1 L2 ----
  A.n = 0; acc = 0;
  for (int t = 0; t < 2; ++t)
    for (int k = 0; k < 2; ++k)
      addd(rp(t * S1r + 124L * NBATCH + CUM1b[k] * NBATCH),
           rp(t * S1r + 124L * NBATCH + CUM1b[k + 1] * NBATCH),
           C1[k], FAN1[k], agg1_self + 10000, agg1_neigh + 10000,
           rp(t * S1r + 143L * NBATCH + (k == 0 ? 0 : 1) * NBATCH), 100);
  agg_kernel<<<dim3((unsigned)acc), dim3(256), 0, stream>>>(A);

  // ---- launch 3: schema1 L3 (final -> spec view 1) ----
  A.n = 0; acc = 0;
  for (int t = 0; t < 2; ++t)
    addd(rp(t * S1r + 143L * NBATCH), rp(t * S1r + 144L * NBATCH),
         1, 3, agg1_self + 15000, agg1_neigh + 15000,
         spec_f + 200 + t * 100, 400);
  agg_kernel<<<dim3((unsigned)acc), dim3(256), 0, stream>>>(A);

  // ---- launch 4: attention + epilogue ----
  attn_final_kernel<<<dim3(NBATCH), dim3(128), 0, stream>>>(
      spec_f, rview_f, nodeids, edgetype, base_embed, reflect,
      vWq, vWk, vWv, vWf, vg, vb, mWq, mWk, mWv, mWf, mg, mb,
      (float*)d_out);
}

// Round 2
// 629.187 us; speedup vs baseline: 1.0432x; 1.0168x over previous
//
#include <hip/hip_runtime.h>
#include <math.h>

// ---------------------------------------------------------------------------
// HybridGNN on MI355X — R5.
// agg v4: Phase B fanout loop templated on compile-time R (r in {3,5,7,9}).
//         R4 post-mortem: occupancy 21->51% moved BW only 1715->1817 GB/s —
//         the binding constraint is per-wave MLP: the rolled runtime-r loop
//         emitted load->waitcnt->add (1-2 outstanding loads/thread, ~10
//         serialized HBM round-trips per u-item on the r=9 segment).
//         Now all R+1 float4 loads issue back-to-back into registers before
//         any use => ~10 outstanding/thread. __launch_bounds__(256,4)
//         (VGPR cap 128) so the R=9 in-flight registers don't spill.
// attn:  unchanged from R3.
// Workspace layout identical to R1 (rows of 100 f32).
// ---------------------------------------------------------------------------

#define NBATCH 512
#define TOTALP 1086
#define RPB 32      // rows per agg block (all segment row counts divide by 32)
#define XSTR 204    // xs LDS row stride (floats), breaks 800-stride bank alias

struct Seg {
  const float* emb;     // gather mode embedding base (null => dense mode)
  const float* selfp;   // dense self rows [N][100]
  const float* neighp;  // dense neighbor rows [N*r][100]
  const int*   ids_s;   // gather: self id array
  const int*   ids_n;   // gather: neighbor id array
  const float* Ws;      // [100][50]
  const float* Wn;      // [100][50]
  float*       outp;    // out row j at outp + j*ostride
  int ss, so;           // self id per-b stride, offset
  int ns, no;           // neigh id per-b stride, offset
  int estride;          // node stride in emb (elements)
  int ostride;
  int c;                // self rows per batch element
  int r;                // fanout
  int blk_begin;        // prefix in fused BLOCK space
};

struct KArgs { Seg seg[14]; int n; };

// Phase B with compile-time fanout R: issue all R+1 loads, then reduce.
template <int R, bool GATHER>
__device__ __forceinline__ void phaseB(const Seg& sg, int j0, int tid,
                                       float* xsh, const int* ids_s_sh,
                                       const int* ids_n_sh) {
  const float rinv = 1.f / (float)R;
  for (int u = tid; u < RPB * 25; u += 256) {
    const int row = u / 25, q4 = (u - row * 25) * 4;
    float4 s4, t[R];
    if (GATHER) {
      s4 = *(const float4*)(sg.emb + (long)ids_s_sh[row] * sg.estride + q4);
#pragma unroll
      for (int rr = 0; rr < R; ++rr)
        t[rr] = *(const float4*)(sg.emb + (long)ids_n_sh[row * R + rr] * sg.estride + q4);
    } else {
      const long j = j0 + row;
      s4 = *(const float4*)(sg.selfp + j * 100 + q4);
#pragma unroll
      for (int rr = 0; rr < R; ++rr)
        t[rr] = *(const float4*)(sg.neighp + (j * R + rr) * 100 + q4);
    }
    float mx = 0.f, my = 0.f, mz = 0.f, mw = 0.f;
#pragma unroll
    for (int rr = 0; rr < R; ++rr) {
      mx += t[rr].x; my += t[rr].y; mz += t[rr].z; mw += t[rr].w;
    }
    *(float4*)&xsh[row * XSTR + q4] = s4;
    float4 mv; mv.x = mx * rinv; mv.y = my * rinv; mv.z = mz * rinv; mv.w = mw * rinv;
    *(float4*)&xsh[row * XSTR + 100 + q4] = mv;
  }
}

__global__ __launch_bounds__(256, 4) void agg_kernel(KArgs P) {
  __shared__ float xsh[RPB * XSTR];     // 26.1 KB  xs[row][0:100]=s, [100:200]=m
  __shared__ int   ids_s_sh[RPB];
  __shared__ int   ids_n_sh[RPB * 9];

  const int blk = blockIdx.x, tid = threadIdx.x;
  int si = 0;
  for (int i = 1; i < P.n; ++i)
    if (blk >= P.seg[i].blk_begin) si = i;
  const Seg sg = P.seg[si];
  const int j0 = (blk - sg.blk_begin) * RPB;
  const int c = sg.c, r = sg.r;

  // ---- ids staging (gather mode) ----
  if (sg.emb) {
    if (tid < RPB) {
      int j = j0 + tid, b = j / c, pos = j - b * c;
      ids_s_sh[tid] = sg.ids_s[(long)b * sg.ss + sg.so + pos];
    }
    for (int u = tid; u < RPB * r; u += 256) {
      int row = u / r, q = u - row * r;
      int j = j0 + row, b = j / c, pos = j - b * c;
      ids_n_sh[u] = sg.ids_n[(long)b * sg.ns + sg.no + pos * r + q];
    }
  }
  __syncthreads();

  // ---- Phase B: gather/load X into LDS (compile-time R => full MLP) ----
  if (sg.emb) {
    switch (r) {
      case 3: phaseB<3, true>(sg, j0, tid, xsh, ids_s_sh, ids_n_sh); break;
      case 5: phaseB<5, true>(sg, j0, tid, xsh, ids_s_sh, ids_n_sh); break;
      case 7: phaseB<7, true>(sg, j0, tid, xsh, ids_s_sh, ids_n_sh); break;
      default: phaseB<9, true>(sg, j0, tid, xsh, ids_s_sh, ids_n_sh); break;
    }
  } else {
    switch (r) {
      case 3: phaseB<3, false>(sg, j0, tid, xsh, ids_s_sh, ids_n_sh); break;
      case 5: phaseB<5, false>(sg, j0, tid, xsh, ids_s_sh, ids_n_sh); break;
      case 7: phaseB<7, false>(sg, j0, tid, xsh, ids_s_sh, ids_n_sh); break;
      default: phaseB<9, false>(sg, j0, tid, xsh, ids_s_sh, ids_n_sh); break;
    }
  }
  __syncthreads();

  // ---- Phase C: 4 rows x 4 cols register-tiled matvec, W from global ----
  // Thread (rg, cq): rows rg*4..rg*4+3, half = (cq<14 ? self : neigh),
  // cols 4*cl..4*cl+3 of that half (cl = cq%14; cl==13 is a pad thread,
  // cl==12 has only 2 valid cols). W rows are 50 floats (8B-aligned at any
  // even col), so load two float2; the second address is clamped for cl>=12
  // so no access ever goes past the 100x50 weight block.
  if (tid < 224) {
    const int rg = tid / 28, cq = tid - rg * 28;
    const int cl = (cq < 14) ? cq : cq - 14;
    const float* Wg = (cq < 14) ? sg.Ws : sg.Wn;
    const int c0 = (cl < 13) ? 4 * cl : 0;
    const int c1 = (cl < 12) ? c0 + 2 : c0;
    const int xoff = (cq < 14) ? 0 : 100;
    float acc[4][4];
#pragma unroll
    for (int i = 0; i < 4; ++i) { acc[i][0] = acc[i][1] = acc[i][2] = acc[i][3] = 0.f; }
    const float* xb = &xsh[(rg * 4) * XSTR + xoff];
#pragma unroll 4
    for (int e = 0; e < 100; ++e) {
      const float2 w0 = *(const float2*)&Wg[e * 50 + c0];
      const float2 w1 = *(const float2*)&Wg[e * 50 + c1];
#pragma unroll
      for (int i = 0; i < 4; ++i) {
        const float a = xb[i * XSTR + e];
        acc[i][0] = fmaf(a, w0.x, acc[i][0]);
        acc[i][1] = fmaf(a, w0.y, acc[i][1]);
        acc[i][2] = fmaf(a, w1.x, acc[i][2]);
        acc[i][3] = fmaf(a, w1.y, acc[i][3]);
      }
    }
    if (cl < 13) {
      const int cbase = (cq < 14 ? 0 : 50) + 4 * cl;
      for (int i = 0; i < 4; ++i) {
        const long j = j0 + rg * 4 + i;
        float* op = sg.outp + j * (long)sg.ostride + cbase;
        if (cl < 12) {
          float4 o;
          o.x = fmaxf(acc[i][0], 0.f); o.y = fmaxf(acc[i][1], 0.f);
          o.z = fmaxf(acc[i][2], 0.f); o.w = fmaxf(acc[i][3], 0.f);
          *(float4*)op = o;
        } else {   // cols 48,49 (or 98,99)
          op[0] = fmaxf(acc[i][0], 0.f);
          op[1] = fmaxf(acc[i][1], 0.f);
        }
      }
    }
  }
}

// ---------------------------------------------------------------------------
// Attention step, W staged through LDS chunks.  x rows at xs[base+i*rs+d].
// ---------------------------------------------------------------------------
__device__ __forceinline__ void attn_step(
    float* xs, int base, int rs, int n,
    const float* Wq, const float* Wk, const float* Wv, const float* Wf,
    const float* g, const float* bb,
    float* ln, float* qq, float* kk, float* vv, float* ot,
    float* sc, float* musd, float* wsh, int tid)
{
  if (tid < n) {
    float mu = 0.f;
    for (int d = 0; d < 100; ++d) mu += xs[base + tid * rs + d];
    mu *= 0.01f;
    float var = 0.f;
    for (int d = 0; d < 100; ++d) {
      float t = xs[base + tid * rs + d] - mu; var = fmaf(t, t, var);
    }
    var *= 0.01f;
    musd[tid * 2]     = mu;
    musd[tid * 2 + 1] = rsqrtf(var + 1e-6f);
  }
  __syncthreads();
  for (int o = tid; o < n * 100; o += 128) {
    int i = o / 100, d = o - i * 100;
    ln[o] = (xs[base + i * rs + d] - musd[i * 2]) * musd[i * 2 + 1] * g[d] + bb[d];
  }
  __syncthreads();

  // ---- q,k,v: thread owns (row i, 4 cols d4), W chunks of 50 e-rows ----
  const bool act = tid < n * 25;
  const int  i   = tid / 25;
  const int  d4  = 4 * (tid - i * 25);
  float aq[4] = {0,0,0,0}, ak[4] = {0,0,0,0}, av[4] = {0,0,0,0};
  for (int ch = 0; ch < 2; ++ch) {
    for (int u = tid; u < 1250; u += 128) {
      int el = u / 25, dd = 4 * (u - el * 25);
      *(float4*)&wsh[el * 300 + dd]       = *(const float4*)&Wq[(ch * 50 + el) * 100 + dd];
      *(float4*)&wsh[el * 300 + 100 + dd] = *(const float4*)&Wk[(ch * 50 + el) * 100 + dd];
      *(float4*)&wsh[el * 300 + 200 + dd] = *(const float4*)&Wv[(ch * 50 + el) * 100 + dd];
    }
    __syncthreads();
    if (act) {
      for (int el = 0; el < 50; ++el) {
        const float lnv = ln[i * 100 + ch * 50 + el];
        const float xv  = xs[base + i * rs + ch * 50 + el];
        const float4 wq = *(const float4*)&wsh[el * 300 + d4];
        const float4 wk = *(const float4*)&wsh[el * 300 + 100 + d4];
        const float4 wv = *(const float4*)&wsh[el * 300 + 200 + d4];
        aq[0] = fmaf(lnv, wq.x, aq[0]); aq[1] = fmaf(lnv, wq.y, aq[1]);
        aq[2] = fmaf(lnv, wq.z, aq[2]); aq[3] = fmaf(lnv, wq.w, aq[3]);
        ak[0] = fmaf(xv,  wk.x, ak[0]); ak[1] = fmaf(xv,  wk.y, ak[1]);
        ak[2] = fmaf(xv,  wk.z, ak[2]); ak[3] = fmaf(xv,  wk.w, ak[3]);
        av[0] = fmaf(xv,  wv.x, av[0]); av[1] = fmaf(xv,  wv.y, av[1]);
        av[2] = fmaf(xv,  wv.z, av[2]); av[3] = fmaf(xv,  wv.w, av[3]);
      }
    }
    __syncthreads();
  }
  if (act) {
#pragma unroll
    for (int jj = 0; jj < 4; ++jj) {
      qq[i * 100 + d4 + jj] = aq[jj];
      kk[i * 100 + d4 + jj] = ak[jj];
      vv[i * 100 + d4 + jj] = av[jj];
    }
  }
  __syncthreads();

  if (tid < n * n) {
    int qi = tid / n, u = tid - qi * n;
    float s = 0.f;
    for (int d = 0; d < 100; ++d) s = fmaf(qq[qi * 100 + d], kk[u * 100 + d], s);
    sc[tid] = s * 0.1f;
  }
  __syncthreads();
  if (tid < n) {
    float mx = sc[tid * n];
    for (int u = 1; u < n; ++u) mx = fmaxf(mx, sc[tid * n + u]);
    float sm = 0.f;
    for (int u = 0; u < n; ++u) {
      float e = expf(sc[tid * n + u] - mx); sc[tid * n + u] = e; sm += e;
    }
    float inv = 1.f / sm;
    for (int u = 0; u < n; ++u) sc[tid * n + u] *= inv;
  }
  __syncthreads();
  for (int o = tid; o < n * 100; o += 128) {
    int ii = o / 100, d = o - ii * 100;
    float a = 0.f;
    for (int u = 0; u < n; ++u) a = fmaf(sc[ii * n + u], vv[u * 100 + d], a);
    ot[o] = a;
  }
  __syncthreads();

  // ---- Wf + residual, chunked through LDS ----
  float af[4] = {0,0,0,0};
  for (int ch = 0; ch < 2; ++ch) {
    for (int u = tid; u < 1250; u += 128) {
      int el = u / 25, dd = 4 * (u - el * 25);
      *(float4*)&wsh[el * 100 + dd] = *(const float4*)&Wf[(ch * 50 + el) * 100 + dd];
    }
    __syncthreads();
    if (act) {
      for (int el = 0; el < 50; ++el) {
        const float ov = ot[i * 100 + ch * 50 + el];
        const float4 wf = *(const float4*)&wsh[el * 100 + d4];
        af[0] = fmaf(ov, wf.x, af[0]); af[1] = fmaf(ov, wf.y, af[1]);
        af[2] = fmaf(ov, wf.z, af[2]); af[3] = fmaf(ov, wf.w, af[3]);
      }
    }
    __syncthreads();
  }
  if (act) {
#pragma unroll
    for (int jj = 0; jj < 4; ++jj)
      xs[base + i * rs + d4 + jj] += af[jj];
  }
  __syncthreads();
}

__global__ __launch_bounds__(128) void attn_final_kernel(
    const float* __restrict__ spec, const float* __restrict__ rview,
    const int* __restrict__ nodeids, const int* __restrict__ edgetype,
    const float* __restrict__ base_embed, const float* __restrict__ reflect,
    const float* vWq, const float* vWk, const float* vWv, const float* vWf,
    const float* vg, const float* vb,
    const float* mWq, const float* mWk, const float* mWv, const float* mWf,
    const float* mg, const float* mb,
    float* __restrict__ out)
{
  __shared__ float xs[600], ln[300], qq[300], kk[300], vv[300], ot[300];
  __shared__ float sc[9], musd[6], r200[200], pooled[200], nrmv[1];
  __shared__ float wsh[15000];
  const int b = blockIdx.x, tid = threadIdx.x;

  for (int o = tid; o < 600; o += 128) {
    int v = o / 200, rem = o - v * 200;
    xs[o] = (v < 2) ? spec[(long)b * 400 + o] : rview[(long)b * 100 + (rem % 100)];
  }
  __syncthreads();

  for (int v = 0; v < 3; ++v)
    attn_step(xs, v * 200, 100, 2, vWq, vWk, vWv, vWf, vg, vb,
              ln, qq, kk, vv, ot, sc, musd, wsh, tid);
  for (int t = 0; t < 2; ++t)
    attn_step(xs, t * 100, 200, 3, mWq, mWk, mWv, mWf, mg, mb,
              ln, qq, kk, vv, ot, sc, musd, wsh, tid);

  for (int o = tid; o < 200; o += 128)
    pooled[o] = (xs[o] + xs[200 + o] + xs[400 + o]) * (1.f / 3.f);
  __syncthreads();

  const int  et  = edgetype[NBATCH + b];
  const long nid = nodeids[b];

  float ar[4] = {0,0,0,0};
  if (tid < 50) {
    const float4 be = *(const float4*)&base_embed[nid * 200 + 4 * tid];
    ar[0] = be.x; ar[1] = be.y; ar[2] = be.z; ar[3] = be.w;
  }
  for (int ch = 0; ch < 2; ++ch) {
    for (int u = tid; u < 2500; u += 128) {
      int dl = u / 50, oo = 4 * (u - dl * 50);
      *(float4*)&wsh[dl * 200 + oo] =
          *(const float4*)&reflect[((long)et * 100 + ch * 50 + dl) * 200 + oo];
    }
    __syncthreads();
    if (tid < 50) {
      for (int dl = 0; dl < 50; ++dl) {
        const float pv = pooled[et * 100 + ch * 50 + dl];
        const float4 rv = *(const float4*)&wsh[dl * 200 + 4 * tid];
        ar[0] = fmaf(pv, rv.x, ar[0]); ar[1] = fmaf(pv, rv.y, ar[1]);
        ar[2] = fmaf(pv, rv.z, ar[2]); ar[3] = fmaf(pv, rv.w, ar[3]);
      }
    }
    __syncthreads();
  }
  if (tid < 50) {
    r200[4 * tid]     = ar[0]; r200[4 * tid + 1] = ar[1];
    r200[4 * tid + 2] = ar[2]; r200[4 * tid + 3] = ar[3];
  }
  __syncthreads();
  if (tid == 0) {
    float ss = 0.f;
    for (int o = 0; o < 200; ++o) ss = fmaf(r200[o], r200[o], ss);
    nrmv[0] = 1.f / fmaxf(sqrtf(ss), 1e-12f);
  }
  __syncthreads();
  for (int o = tid; o < 200; o += 128)
    out[(long)b * 200 + o] = r200[o] * nrmv[0];
}

// ---------------------------------------------------------------------------
extern "C" void kernel_launch(void* const* d_in, const int* in_sizes, int n_in,
                              void* d_out, int out_size, void* d_ws, size_t ws_size,
                              hipStream_t stream) {
  (void)in_sizes; (void)n_in; (void)out_size; (void)ws_size;
  const int*   nodeids          = (const int*)d_in[0];
  const int*   edgetype         = (const int*)d_in[1];
  const int*   neighbors        = (const int*)d_in[2];
  const int*   random_neighbors = (const int*)d_in[3];
  const float* base_embed       = (const float*)d_in[4];
  const float* type_embed       = (const float*)d_in[5];
  const float* rw_embed         = (const float*)d_in[6];
  const float* reflect          = (const float*)d_in[7];
  const float* agg0_self        = (const float*)d_in[8];
  const float* agg0_neigh       = (const float*)d_in[9];
  const float* agg1_self        = (const float*)d_in[10];
  const float* agg1_neigh       = (const float*)d_in[11];
  const float* rand_self        = (const float*)d_in[12];
  const float* rand_neigh       = (const float*)d_in[13];
  const float* vWq = (const float*)d_in[14];
  const float* vWk = (const float*)d_in[15];
  const float* vWv = (const float*)d_in[16];
  const float* vWf = (const float*)d_in[17];
  const float* vg  = (const float*)d_in[18];
  const float* vb  = (const float*)d_in[19];
  const float* mWq = (const float*)d_in[20];
  const float* mWk = (const float*)d_in[21];
  const float* mWv = (const float*)d_in[22];
  const float* mWf = (const float*)d_in[23];
  const float* mg  = (const float*)d_in[24];
  const float* mb  = (const float*)d_in[25];

  float* ws = (float*)d_ws;
  const long S1r = 147L * NBATCH;                 // schema1 rows per t
  auto rp = [&](long rows) { return ws + rows * 100; };
  float* spec_f  = ws + 306L * NBATCH * 100;      // [B][2][2][100]
  float* rview_f = spec_f + (long)NBATCH * 400;   // [B][100]

  const int  OFF1[4] = {18, 21, 36, 141};
  const int  FAN1[4] = {3, 5, 7, 9};
  const int  C1[4]   = {1, 3, 15, 105};
  const long CUM1[4]  = {0, 1, 4, 19};
  const long CUM1b[3] = {0, 1, 4};

  KArgs A; long acc = 0;   // acc in BLOCKS (32 rows each)
  auto addg = [&](const float* emb, int estride,
                  const int* isrc, int ss, int so, int c,
                  const int* insrc, int nstr, int no, int r,
                  const float* Ws, const float* Wn, float* outp, int ostride) {
    Seg& s = A.seg[A.n++];
    s.emb = emb; s.selfp = nullptr; s.neighp = nullptr;
    s.ids_s = isrc; s.ids_n = insrc;
    s.Ws = Ws; s.Wn = Wn; s.outp = outp;
    s.ss = ss; s.so = so; s.ns = nstr; s.no = no;
    s.estride = estride; s.ostride = ostride;
    s.c = c; s.r = r; s.blk_begin = (int)acc;
    acc += (long)c * NBATCH / RPB;
  };
  auto addd = [&](const float* selfp, const float* neighp, int c, int r,
                  const float* Ws, const float* Wn, float* outp, int ostride) {
    Seg& s = A.seg[A.n++];
    s.emb = nullptr; s.selfp = selfp; s.neighp = neighp;
    s.ids_s = nullptr; s.ids_n = nullptr;
    s.Ws = Ws; s.Wn = Wn; s.outp = outp;
    s.ss = 0; s.so = 0; s.ns = 0; s.no = 0; s.estride = 0; s.ostride = ostride;
    s.c = c; s.r = r; s.blk_begin = (int)acc;
    acc += (long)c * NBATCH / RPB;
  };

  // ---- launch 0: all level-0 (gather) pairs ----
  A.n = 0; acc = 0;
  for (int t = 0; t < 2; ++t)
    for (int k = 0; k < 4; ++k) {
      const float* emb = type_embed + (t * 2 + 1) * 100;
      if (k == 0)
        addg(emb, 400, nodeids, 1, 0, 1,
             neighbors, 2 * TOTALP, t * TOTALP + OFF1[k], FAN1[k],
             agg1_self, agg1_neigh, rp(t * S1r + CUM1[k] * NBATCH), 100);
      else
        addg(emb, 400, neighbors, 2 * TOTALP, t * TOTALP + OFF1[k - 1], C1[k],
             neighbors, 2 * TOTALP, t * TOTALP + OFF1[k], FAN1[k],
             agg1_self, agg1_neigh, rp(t * S1r + CUM1[k] * NBATCH), 100);
    }
  for (int t = 0; t < 2; ++t)
    for (int k = 0; k < 2; ++k) {
      const float* emb = type_embed + (t * 2 + 0) * 100;
      long obase = 294L * NBATCH + (long)t * 4 * NBATCH + (k == 0 ? 0 : 1) * NBATCH;
      if (k == 0)
        addg(emb, 400, nodeids, 1, 0, 1,
             neighbors, 2 * TOTALP, t * TOTALP + 0, 3,
             agg0_self, agg0_neigh, rp(obase), 100);
      else
        addg(emb, 400, neighbors, 2 * TOTALP, t * TOTALP + 0, 3,
             neighbors, 2 * TOTALP, t * TOTALP + 3, 5,
             agg0_self, agg0_neigh, rp(obase), 100);
    }
  for (int k = 0; k < 2; ++k) {
    long obase = 302L * NBATCH + (k == 0 ? 0 : 1) * NBATCH;
    if (k == 0)
      addg(rw_embed, 100, nodeids, 1, 0, 1,
           random_neighbors, 18, 0, 3, rand_self, rand_neigh, rp(obase), 100);
    else
      addg(rw_embed, 100, random_neighbors, 18, 0, 3,
           random_neighbors, 18, 3, 5, rand_self, rand_neigh, rp(obase), 100);
  }
  agg_kernel<<<dim3((unsigned)acc), dim3(256), 0, stream>>>(A);

  // ---- launch 1: schema1 L1, schema0 L1 (final), random L1 (final) ----
  A.n = 0; acc = 0;
  for (int t = 0; t < 2; ++t)
    for (int k = 0; k < 3; ++k)
      addd(rp(t * S1r + CUM1[k] * NBATCH), rp(t * S1r + CUM1[k + 1] * NBATCH),
           C1[k], FAN1[k], agg1_self + 5000, agg1_neigh + 5000,
           rp(t * S1r + 124L * NBATCH + CUM1b[k] * NBATCH), 100);
  for (int t = 0; t < 2; ++t)
    addd(rp(294L * NBATCH + (long)t * 4 * NBATCH),
         rp(294L * NBATCH + (long)t * 4 * NBATCH + NBATCH),
         1, 3, agg0_self + 5000, agg0_neigh + 5000, spec_f + t * 100, 400);
  addd(rp(302L * NBATCH), rp(303L * NBATCH), 1, 3,
       rand_self + 5000, rand_neigh + 5000, rview_f, 100);
  agg_kernel<<<dim3((unsigned)acc), dim3(256), 0, stream>>>(A);

  // ---- launch 2: schema1 L2 ----
  A.n = 0; acc = 0;
  for (int t = 0; t < 2; ++t)
    for (int k = 0; k < 2; ++k)
      addd(rp(t * S1r + 124L * NBATCH + CUM1b[k] * NBATCH),
           rp(t * S1r + 124L * NBATCH + CUM1b[k + 1] * NBATCH),
           C1[k], FAN1[k], agg1_self + 10000, agg1_neigh + 10000,
           rp(t * S1r + 143L * NBATCH + (k == 0 ? 0 : 1) * NBATCH), 100);
  agg_kernel<<<dim3((unsigned)acc), dim3(256), 0, stream>>>(A);

  // ---- launch 3: schema1 L3 (final -> spec view 1) ----
  A.n = 0; acc = 0;
  for (int t = 0; t < 2; ++t)
    addd(rp(t * S1r + 143L * NBATCH), rp(t * S1r + 144L * NBATCH),
         1, 3, agg1_self + 15000, agg1_neigh + 15000,
         spec_f + 200 + t * 100, 400);
  agg_kernel<<<dim3((unsigned)acc), dim3(256), 0, stream>>>(A);

  // ---- launch 4: attention + epilogue ----
  attn_final_kernel<<<dim3(NBATCH), dim3(128), 0, stream>>>(
      spec_f, rview_f, nodeids, edgetype, base_embed, reflect,
      vWq, vWk, vWv, vWf, vg, vb, mWq, mWk, mWv, mWf, mg, mb,
      (float*)d_out);
}

// Round 5
// 617.771 us; speedup vs baseline: 1.0625x; 1.0185x over previous
//
#include <hip/hip_runtime.h>
#include <math.h>

// ---------------------------------------------------------------------------
// HybridGNN on MI355X — R6 (second resubmit; Rounds 3 and 4 both failed with
// GPUAcquisitionTimeout — kernel has never run).
// R5 post-mortem: compiler ignored the load batching (VGPR stayed 44); BW
// pinned at ~1.85 TB/s regardless of occupancy/MLP => launch0 is at the
// random-line gather throughput ceiling (296 MB of 128B-line requests vs
// ~110 MB unique). Launch0 left alone this round (floor ~150-190 us).
// The real anomaly: total 629 us but launch0 only 193 => ~436 us hidden in
// launches 1-4 (all <191 us so invisible in top-5).
// R6 changes:
//  - agg split into agg_gather / agg_dense (identical math) for attribution.
//  - attn v3: wsh weight-staging LDS deleted; Wq/Wk/Wv/Wf/reflect read
//    directly from global (L1/L2-resident, shared by all 512 blocks).
//    Barriers per step 14->7, LDS 70KB->10KB, FMA order preserved exactly.
// ---------------------------------------------------------------------------

#define NBATCH 512
#define TOTALP 1086
#define RPB 32      // rows per agg block (all segment row counts divide by 32)
#define XSTR 204    // xs LDS row stride (floats), breaks 800-stride bank alias

struct Seg {
  const float* emb;     // gather mode embedding base (null => dense mode)
  const float* selfp;   // dense self rows [N][100]
  const float* neighp;  // dense neighbor rows [N*r][100]
  const int*   ids_s;   // gather: self id array
  const int*   ids_n;   // gather: neighbor id array
  const float* Ws;      // [100][50]
  const float* Wn;      // [100][50]
  float*       outp;    // out row j at outp + j*ostride
  int ss, so;           // self id per-b stride, offset
  int ns, no;           // neigh id per-b stride, offset
  int estride;          // node stride in emb (elements)
  int ostride;
  int c;                // self rows per batch element
  int r;                // fanout
  int blk_begin;        // prefix in fused BLOCK space
};

struct KArgs { Seg seg[14]; int n; };

// ---- shared Phase C: 4 rows x 4 cols register-tiled matvec, W from global --
__device__ __forceinline__ void phaseC(const Seg& sg, int j0, int tid,
                                       const float* xsh) {
  if (tid < 224) {
    const int rg = tid / 28, cq = tid - rg * 28;
    const int cl = (cq < 14) ? cq : cq - 14;
    const float* Wg = (cq < 14) ? sg.Ws : sg.Wn;
    const int c0 = (cl < 13) ? 4 * cl : 0;
    const int c1 = (cl < 12) ? c0 + 2 : c0;
    const int xoff = (cq < 14) ? 0 : 100;
    float acc[4][4];
#pragma unroll
    for (int i = 0; i < 4; ++i) { acc[i][0] = acc[i][1] = acc[i][2] = acc[i][3] = 0.f; }
    const float* xb = &xsh[(rg * 4) * XSTR + xoff];
#pragma unroll 4
    for (int e = 0; e < 100; ++e) {
      const float2 w0 = *(const float2*)&Wg[e * 50 + c0];
      const float2 w1 = *(const float2*)&Wg[e * 50 + c1];
#pragma unroll
      for (int i = 0; i < 4; ++i) {
        const float a = xb[i * XSTR + e];
        acc[i][0] = fmaf(a, w0.x, acc[i][0]);
        acc[i][1] = fmaf(a, w0.y, acc[i][1]);
        acc[i][2] = fmaf(a, w1.x, acc[i][2]);
        acc[i][3] = fmaf(a, w1.y, acc[i][3]);
      }
    }
    if (cl < 13) {
      const int cbase = (cq < 14 ? 0 : 50) + 4 * cl;
      for (int i = 0; i < 4; ++i) {
        const long j = j0 + rg * 4 + i;
        float* op = sg.outp + j * (long)sg.ostride + cbase;
        if (cl < 12) {
          float4 o;
          o.x = fmaxf(acc[i][0], 0.f); o.y = fmaxf(acc[i][1], 0.f);
          o.z = fmaxf(acc[i][2], 0.f); o.w = fmaxf(acc[i][3], 0.f);
          *(float4*)op = o;
        } else {   // cols 48,49 (or 98,99)
          op[0] = fmaxf(acc[i][0], 0.f);
          op[1] = fmaxf(acc[i][1], 0.f);
        }
      }
    }
  }
}

// ---- gather-mode Phase B (compile-time fanout R) ----
template <int R>
__device__ __forceinline__ void phaseB_g(const Seg& sg, int tid, float* xsh,
                                         const int* ids_s_sh, const int* ids_n_sh) {
  const float rinv = 1.f / (float)R;
  for (int u = tid; u < RPB * 25; u += 256) {
    const int row = u / 25, q4 = (u - row * 25) * 4;
    float4 s4 = *(const float4*)(sg.emb + (long)ids_s_sh[row] * sg.estride + q4);
    float mx = 0.f, my = 0.f, mz = 0.f, mw = 0.f;
#pragma unroll
    for (int rr = 0; rr < R; ++rr) {
      const float4 t = *(const float4*)(sg.emb + (long)ids_n_sh[row * R + rr] * sg.estride + q4);
      mx += t.x; my += t.y; mz += t.z; mw += t.w;
    }
    *(float4*)&xsh[row * XSTR + q4] = s4;
    float4 mv; mv.x = mx * rinv; mv.y = my * rinv; mv.z = mz * rinv; mv.w = mw * rinv;
    *(float4*)&xsh[row * XSTR + 100 + q4] = mv;
  }
}

// ---- dense-mode Phase B (compile-time fanout R) ----
template <int R>
__device__ __forceinline__ void phaseB_d(const Seg& sg, int j0, int tid, float* xsh) {
  const float rinv = 1.f / (float)R;
  for (int u = tid; u < RPB * 25; u += 256) {
    const int row = u / 25, q4 = (u - row * 25) * 4;
    const long j = j0 + row;
    float4 s4 = *(const float4*)(sg.selfp + j * 100 + q4);
    float mx = 0.f, my = 0.f, mz = 0.f, mw = 0.f;
#pragma unroll
    for (int rr = 0; rr < R; ++rr) {
      const float4 t = *(const float4*)(sg.neighp + (j * R + rr) * 100 + q4);
      mx += t.x; my += t.y; mz += t.z; mw += t.w;
    }
    *(float4*)&xsh[row * XSTR + q4] = s4;
    float4 mv; mv.x = mx * rinv; mv.y = my * rinv; mv.z = mz * rinv; mv.w = mw * rinv;
    *(float4*)&xsh[row * XSTR + 100 + q4] = mv;
  }
}

__global__ __launch_bounds__(256, 4) void agg_gather(KArgs P) {
  __shared__ float xsh[RPB * XSTR];
  __shared__ int   ids_s_sh[RPB];
  __shared__ int   ids_n_sh[RPB * 9];

  const int blk = blockIdx.x, tid = threadIdx.x;
  int si = 0;
  for (int i = 1; i < P.n; ++i)
    if (blk >= P.seg[i].blk_begin) si = i;
  const Seg sg = P.seg[si];
  const int j0 = (blk - sg.blk_begin) * RPB;
  const int c = sg.c, r = sg.r;

  if (tid < RPB) {
    int j = j0 + tid, b = j / c, pos = j - b * c;
    ids_s_sh[tid] = sg.ids_s[(long)b * sg.ss + sg.so + pos];
  }
  for (int u = tid; u < RPB * r; u += 256) {
    int row = u / r, q = u - row * r;
    int j = j0 + row, b = j / c, pos = j - b * c;
    ids_n_sh[u] = sg.ids_n[(long)b * sg.ns + sg.no + pos * r + q];
  }
  __syncthreads();

  switch (r) {
    case 3: phaseB_g<3>(sg, tid, xsh, ids_s_sh, ids_n_sh); break;
    case 5: phaseB_g<5>(sg, tid, xsh, ids_s_sh, ids_n_sh); break;
    case 7: phaseB_g<7>(sg, tid, xsh, ids_s_sh, ids_n_sh); break;
    default: phaseB_g<9>(sg, tid, xsh, ids_s_sh, ids_n_sh); break;
  }
  __syncthreads();

  phaseC(sg, j0, tid, xsh);
}

__global__ __launch_bounds__(256, 4) void agg_dense(KArgs P) {
  __shared__ float xsh[RPB * XSTR];

  const int blk = blockIdx.x, tid = threadIdx.x;
  int si = 0;
  for (int i = 1; i < P.n; ++i)
    if (blk >= P.seg[i].blk_begin) si = i;
  const Seg sg = P.seg[si];
  const int j0 = (blk - sg.blk_begin) * RPB;

  switch (sg.r) {
    case 3: phaseB_d<3>(sg, j0, tid, xsh); break;
    case 5: phaseB_d<5>(sg, j0, tid, xsh); break;
    default: phaseB_d<7>(sg, j0, tid, xsh); break;
  }
  __syncthreads();

  phaseC(sg, j0, tid, xsh);
}

// ---------------------------------------------------------------------------
// Attention step, weights read directly from global (L1/L2-resident; all
// blocks share the same 40KB matrices).  x rows at xs[base+i*rs+d].
// FMA order identical to the staged version (el = 0..99 sequential).
// ---------------------------------------------------------------------------
__device__ __forceinline__ void attn_step(
    float* xs, int base, int rs, int n,
    const float* __restrict__ Wq, const float* __restrict__ Wk,
    const float* __restrict__ Wv, const float* __restrict__ Wf,
    const float* __restrict__ g, const float* __restrict__ bb,
    float* ln, float* qq, float* kk, float* vv, float* ot,
    float* sc, float* musd, int tid)
{
  if (tid < n) {
    float mu = 0.f;
    for (int d = 0; d < 100; ++d) mu += xs[base + tid * rs + d];
    mu *= 0.01f;
    float var = 0.f;
    for (int d = 0; d < 100; ++d) {
      float t = xs[base + tid * rs + d] - mu; var = fmaf(t, t, var);
    }
    var *= 0.01f;
    musd[tid * 2]     = mu;
    musd[tid * 2 + 1] = rsqrtf(var + 1e-6f);
  }
  __syncthreads();
  for (int o = tid; o < n * 100; o += 128) {
    int i = o / 100, d = o - i * 100;
    ln[o] = (xs[base + i * rs + d] - musd[i * 2]) * musd[i * 2 + 1] * g[d] + bb[d];
  }
  __syncthreads();

  // ---- q,k,v: thread owns (row i, 4 cols d4), W direct from global ----
  const bool act = tid < n * 25;
  const int  i   = tid / 25;
  const int  d4  = 4 * (tid - i * 25);
  if (act) {
    float aq[4] = {0,0,0,0}, ak[4] = {0,0,0,0}, av[4] = {0,0,0,0};
#pragma unroll 4
    for (int el = 0; el < 100; ++el) {
      const float lnv = ln[i * 100 + el];
      const float xv  = xs[base + i * rs + el];
      const float4 wq = *(const float4*)&Wq[el * 100 + d4];
      const float4 wk = *(const float4*)&Wk[el * 100 + d4];
      const float4 wv = *(const float4*)&Wv[el * 100 + d4];
      aq[0] = fmaf(lnv, wq.x, aq[0]); aq[1] = fmaf(lnv, wq.y, aq[1]);
      aq[2] = fmaf(lnv, wq.z, aq[2]); aq[3] = fmaf(lnv, wq.w, aq[3]);
      ak[0] = fmaf(xv,  wk.x, ak[0]); ak[1] = fmaf(xv,  wk.y, ak[1]);
      ak[2] = fmaf(xv,  wk.z, ak[2]); ak[3] = fmaf(xv,  wk.w, ak[3]);
      av[0] = fmaf(xv,  wv.x, av[0]); av[1] = fmaf(xv,  wv.y, av[1]);
      av[2] = fmaf(xv,  wv.z, av[2]); av[3] = fmaf(xv,  wv.w, av[3]);
    }
#pragma unroll
    for (int jj = 0; jj < 4; ++jj) {
      qq[i * 100 + d4 + jj] = aq[jj];
      kk[i * 100 + d4 + jj] = ak[jj];
      vv[i * 100 + d4 + jj] = av[jj];
    }
  }
  __syncthreads();

  if (tid < n * n) {
    int qi = tid / n, u = tid - qi * n;
    float s = 0.f;
    for (int d = 0; d < 100; ++d) s = fmaf(qq[qi * 100 + d], kk[u * 100 + d], s);
    sc[tid] = s * 0.1f;
  }
  __syncthreads();
  if (tid < n) {
    float mx = sc[tid * n];
    for (int u = 1; u < n; ++u) mx = fmaxf(mx, sc[tid * n + u]);
    float sm = 0.f;
    for (int u = 0; u < n; ++u) {
      float e = expf(sc[tid * n + u] - mx); sc[tid * n + u] = e; sm += e;
    }
    float inv = 1.f / sm;
    for (int u = 0; u < n; ++u) sc[tid * n + u] *= inv;
  }
  __syncthreads();
  for (int o = tid; o < n * 100; o += 128) {
    int ii = o / 100, d = o - ii * 100;
    float a = 0.f;
    for (int u = 0; u < n; ++u) a = fmaf(sc[ii * n + u], vv[u * 100 + d], a);
    ot[o] = a;
  }
  __syncthreads();

  // ---- Wf + residual, direct from global ----
  if (act) {
    float af[4] = {0,0,0,0};
#pragma unroll 4
    for (int el = 0; el < 100; ++el) {
      const float ov = ot[i * 100 + el];
      const float4 wf = *(const float4*)&Wf[el * 100 + d4];
      af[0] = fmaf(ov, wf.x, af[0]); af[1] = fmaf(ov, wf.y, af[1]);
      af[2] = fmaf(ov, wf.z, af[2]); af[3] = fmaf(ov, wf.w, af[3]);
    }
#pragma unroll
    for (int jj = 0; jj < 4; ++jj)
      xs[base + i * rs + d4 + jj] += af[jj];
  }
  __syncthreads();
}

__global__ __launch_bounds__(128) void attn_final_kernel(
    const float* __restrict__ spec, const float* __restrict__ rview,
    const int* __restrict__ nodeids, const int* __restrict__ edgetype,
    const float* __restrict__ base_embed, const float* __restrict__ reflect,
    const float* __restrict__ vWq, const float* __restrict__ vWk,
    const float* __restrict__ vWv, const float* __restrict__ vWf,
    const float* __restrict__ vg, const float* __restrict__ vb,
    const float* __restrict__ mWq, const float* __restrict__ mWk,
    const float* __restrict__ mWv, const float* __restrict__ mWf,
    const float* __restrict__ mg, const float* __restrict__ mb,
    float* __restrict__ out)
{
  __shared__ float xs[600], ln[300], qq[300], kk[300], vv[300], ot[300];
  __shared__ float sc[9], musd[6], r200[200], pooled[200], nrmv[1];
  const int b = blockIdx.x, tid = threadIdx.x;

  for (int o = tid; o < 600; o += 128) {
    int v = o / 200, rem = o - v * 200;
    xs[o] = (v < 2) ? spec[(long)b * 400 + o] : rview[(long)b * 100 + (rem % 100)];
  }
  __syncthreads();

  for (int v = 0; v < 3; ++v)
    attn_step(xs, v * 200, 100, 2, vWq, vWk, vWv, vWf, vg, vb,
              ln, qq, kk, vv, ot, sc, musd, tid);
  for (int t = 0; t < 2; ++t)
    attn_step(xs, t * 100, 200, 3, mWq, mWk, mWv, mWf, mg, mb,
              ln, qq, kk, vv, ot, sc, musd, tid);

  for (int o = tid; o < 200; o += 128)
    pooled[o] = (xs[o] + xs[200 + o] + xs[400 + o]) * (1.f / 3.f);
  __syncthreads();

  const int  et  = edgetype[NBATCH + b];
  const long nid = nodeids[b];

  float ar[4] = {0,0,0,0};
  if (tid < 50) {
    const float4 be = *(const float4*)&base_embed[nid * 200 + 4 * tid];
    ar[0] = be.x; ar[1] = be.y; ar[2] = be.z; ar[3] = be.w;
#pragma unroll 4
    for (int dl = 0; dl < 100; ++dl) {
      const float pv = pooled[et * 100 + dl];
      const float4 rv = *(const float4*)&reflect[((long)et * 100 + dl) * 200 + 4 * tid];
      ar[0] = fmaf(pv, rv.x, ar[0]); ar[1] = fmaf(pv, rv.y, ar[1]);
      ar[2] = fmaf(pv, rv.z, ar[2]); ar[3] = fmaf(pv, rv.w, ar[3]);
    }
    r200[4 * tid]     = ar[0]; r200[4 * tid + 1] = ar[1];
    r200[4 * tid + 2] = ar[2]; r200[4 * tid + 3] = ar[3];
  }
  __syncthreads();
  if (tid == 0) {
    float ss = 0.f;
    for (int o = 0; o < 200; ++o) ss = fmaf(r200[o], r200[o], ss);
    nrmv[0] = 1.f / fmaxf(sqrtf(ss), 1e-12f);
  }
  __syncthreads();
  for (int o = tid; o < 200; o += 128)
    out[(long)b * 200 + o] = r200[o] * nrmv[0];
}

// ---------------------------------------------------------------------------
extern "C" void kernel_launch(void* const* d_in, const int* in_sizes, int n_in,
                              void* d_out, int out_size, void* d_ws, size_t ws_size,
                              hipStream_t stream) {
  (void)in_sizes; (void)n_in; (void)out_size; (void)ws_size;
  const int*   nodeids          = (const int*)d_in[0];
  const int*   edgetype         = (const int*)d_in[1];
  const int*   neighbors        = (const int*)d_in[2];
  const int*   random_neighbors = (const int*)d_in[3];
  const float* base_embed       = (const float*)d_in[4];
  const float* type_embed       = (const float*)d_in[5];
  const float* rw_embed         = (const float*)d_in[6];
  const float* reflect          = (const float*)d_in[7];
  const float* agg0_self        = (const float*)d_in[8];
  const float* agg0_neigh       = (const float*)d_in[9];
  const float* agg1_self        = (const float*)d_in[10];
  const float* agg1_neigh       = (const float*)d_in[11];
  const float* rand_self        = (const float*)d_in[12];
  const float* rand_neigh       = (const float*)d_in[13];
  const float* vWq = (const float*)d_in[14];
  const float* vWk = (const float*)d_in[15];
  const float* vWv = (const float*)d_in[16];
  const float* vWf = (const float*)d_in[17];
  const float* vg  = (const float*)d_in[18];
  const float* vb  = (const float*)d_in[19];
  const float* mWq = (const float*)d_in[20];
  const float* mWk = (const float*)d_in[21];
  const float* mWv = (const float*)d_in[22];
  const float* mWf = (const float*)d_in[23];
  const float* mg  = (const float*)d_in[24];
  const float* mb  = (const float*)d_in[25];

  float* ws = (float*)d_ws;
  const long S1r = 147L * NBATCH;                 // schema1 rows per t
  auto rp = [&](long rows) { return ws + rows * 100; };
  float* spec_f  = ws + 306L * NBATCH * 100;      // [B][2][2][100]
  float* rview_f = spec_f + (long)NBATCH * 400;   // [B][100]

  const int  OFF1[4] = {18, 21, 36, 141};
  const int  FAN1[4] = {3, 5, 7, 9};
  const int  C1[4]   = {1, 3, 15, 105};
  const long CUM1[4]  = {0, 1, 4, 19};
  const long CUM1b[3] = {0, 1, 4};

  KArgs A; long acc = 0;   // acc in BLOCKS (32 rows each)
  auto addg = [&](const float* emb, int estride,
                  const int* isrc, int ss, int so, int c,
                  const int* insrc, int nstr, int no, int r,
                  const float* Ws, const float* Wn, float* outp, int ostride) {
    Seg& s = A.seg[A.n++];
    s.emb = emb; s.selfp = nullptr; s.neighp = nullptr;
    s.ids_s = isrc; s.ids_n = insrc;
    s.Ws = Ws; s.Wn = Wn; s.outp = outp;
    s.ss = ss; s.so = so; s.ns = nstr; s.no = no;
    s.estride = estride; s.ostride = ostride;
    s.c = c; s.r = r; s.blk_begin = (int)acc;
    acc += (long)c * NBATCH / RPB;
  };
  auto addd = [&](const float* selfp, const float* neighp, int c, int r,
                  const float* Ws, const float* Wn, float* outp, int ostride) {
    Seg& s = A.seg[A.n++];
    s.emb = nullptr; s.selfp = selfp; s.neighp = neighp;
    s.ids_s = nullptr; s.ids_n = nullptr;
    s.Ws = Ws; s.Wn = Wn; s.outp = outp;
    s.ss = 0; s.so = 0; s.ns = 0; s.no = 0; s.estride = 0; s.ostride = ostride;
    s.c = c; s.r = r; s.blk_begin = (int)acc;
    acc += (long)c * NBATCH / RPB;
  };

  // ---- launch 0: all level-0 (gather) pairs ----
  A.n = 0; acc = 0;
  for (int t = 0; t < 2; ++t)
    for (int k = 0; k < 4; ++k) {
      const float* emb = type_embed + (t * 2 + 1) * 100;
      if (k == 0)
        addg(emb, 400, nodeids, 1, 0, 1,
             neighbors, 2 * TOTALP, t * TOTALP + OFF1[k], FAN1[k],
             agg1_self, agg1_neigh, rp(t * S1r + CUM1[k] * NBATCH), 100);
      else
        addg(emb, 400, neighbors, 2 * TOTALP, t * TOTALP + OFF1[k - 1], C1[k],
             neighbors, 2 * TOTALP, t * TOTALP + OFF1[k], FAN1[k],
             agg1_self, agg1_neigh, rp(t * S1r + CUM1[k] * NBATCH), 100);
    }
  for (int t = 0; t < 2; ++t)
    for (int k = 0; k < 2; ++k) {
      const float* emb = type_embed + (t * 2 + 0) * 100;
      long obase = 294L * NBATCH + (long)t * 4 * NBATCH + (k == 0 ? 0 : 1) * NBATCH;
      if (k == 0)
        addg(emb, 400, nodeids, 1, 0, 1,
             neighbors, 2 * TOTALP, t * TOTALP + 0, 3,
             agg0_self, agg0_neigh, rp(obase), 100);
      else
        addg(emb, 400, neighbors, 2 * TOTALP, t * TOTALP + 0, 3,
             neighbors, 2 * TOTALP, t * TOTALP + 3, 5,
             agg0_self, agg0_neigh, rp(obase), 100);
    }
  for (int k = 0; k < 2; ++k) {
    long obase = 302L * NBATCH + (k == 0 ? 0 : 1) * NBATCH;
    if (k == 0)
      addg(rw_embed, 100, nodeids, 1, 0, 1,
           random_neighbors, 18, 0, 3, rand_self, rand_neigh, rp(obase), 100);
    else
      addg(rw_embed, 100, random_neighbors, 18, 0, 3,
           random_neighbors, 18, 3, 5, rand_self, rand_neigh, rp(obase), 100);
  }
  agg_gather<<<dim3((unsigned)acc), dim3(256), 0, stream>>>(A);

  // ---- launch 1: schema1 L1, schema0 L1 (final), random L1 (final) ----
  A.n = 0; acc = 0;
  for (int t = 0; t < 2; ++t)
    for (int k = 0; k < 3; ++k)
      addd(rp(t * S1r + CUM1[k] * NBATCH), rp(t * S1r + CUM1[k + 1] * NBATCH),
           C1[k], FAN1[k], agg1_self + 5000, agg1_neigh + 5000,
           rp(t * S1r + 124L * NBATCH + CUM1b[k] * NBATCH), 100);
  for (int t = 0; t < 2; ++t)
    addd(rp(294L * NBATCH + (long)t * 4 * NBATCH),
         rp(294L * NBATCH + (long)t * 4 * NBATCH + NBATCH),
         1, 3, agg0_self + 5000, agg0_neigh + 5000, spec_f + t * 100, 400);
  addd(rp(302L * NBATCH), rp(303L * NBATCH), 1, 3,
       rand_self + 5000, rand_neigh + 5000, rview_f, 100);
  agg_dense<<<dim3((unsigned)acc), dim3(256), 0, stream>>>(A);

  // ---- launch 2: schema1 L2 ----
  A.n = 0; acc = 0;
  for (int t = 0; t < 2; ++t)
    for (int k = 0; k < 2; ++k)
      addd(rp(t * S1r + 124L * NBATCH + CUM1b[k] * NBATCH),
           rp(t * S1r + 124L * NBATCH + CUM1b[k + 1] * NBATCH),
           C1[k], FAN1[k], agg1_self + 10000, agg1_neigh + 10000,
           rp(t * S1r + 143L * NBATCH + (k == 0 ? 0 : 1) * NBATCH), 100);
  agg_dense<<<dim3((unsigned)acc), dim3(256), 0, stream>>>(A);

  // ---- launch 3: schema1 L3 (final -> spec view 1) ----
  A.n = 0; acc = 0;
  for (int t = 0; t < 2; ++t)
    addd(rp(t * S1r + 143L * NBATCH), rp(t * S1r + 144L * NBATCH),
         1, 3, agg1_self + 15000, agg1_neigh + 15000,
         spec_f + 200 + t * 100, 400);
  agg_dense<<<dim3((unsigned)acc), dim3(256), 0, stream>>>(A);

  // ---- launch 4: attention + epilogue ----
  attn_final_kernel<<<dim3(NBATCH), dim3(128), 0, stream>>>(
      spec_f, rview_f, nodeids, edgetype, base_embed, reflect,
      vWq, vWk, vWv, vWf, vg, vb, mWq, mWk, mWv, mWf, mg, mb,
      (float*)d_out);
}

// Round 6
// 590.801 us; speedup vs baseline: 1.1110x; 1.0457x over previous
//
#include <hip/hip_runtime.h>
#include <math.h>

// ---------------------------------------------------------------------------
// HybridGNN on MI355X — R7.
// R6 post-mortem: agg_gather control unchanged (192.9us); attn staging removal
// saved only ~11us. 425us remains invisible (<191.5us/dispatch). Theory A:
// attn critical path is latency-bound (5 sequential steps x 7 barriers, <=100
// active of 128 threads, 4 waves/CU). Theory B: fixed per-iteration dispatch
// overhead. R7 discriminates + attacks A:
//  - attn v4: 384-thread block, 3 groups of 128. The 3 view steps (disjoint
//    xs slices) run CONCURRENTLY, then the 2 meta steps (disjoint slices)
//    run concurrently (group 2 runs a 7-barrier no-op to keep __syncthreads
//    counts uniform). attn_step body unchanged => identical numerics.
//    Critical path 5 steps -> 2.
//  - dense kernels renamed agg_dense1/2/3 for attribution.
//  - agg_gather untouched (control; at random-gather ceiling ~1.86 TB/s).
// ---------------------------------------------------------------------------

#define NBATCH 512
#define TOTALP 1086
#define RPB 32      // rows per agg block (all segment row counts divide by 32)
#define XSTR 204    // xs LDS row stride (floats), breaks 800-stride bank alias

struct Seg {
  const float* emb;     // gather mode embedding base (null => dense mode)
  const float* selfp;   // dense self rows [N][100]
  const float* neighp;  // dense neighbor rows [N*r][100]
  const int*   ids_s;   // gather: self id array
  const int*   ids_n;   // gather: neighbor id array
  const float* Ws;      // [100][50]
  const float* Wn;      // [100][50]
  float*       outp;    // out row j at outp + j*ostride
  int ss, so;           // self id per-b stride, offset
  int ns, no;           // neigh id per-b stride, offset
  int estride;          // node stride in emb (elements)
  int ostride;
  int c;                // self rows per batch element
  int r;                // fanout
  int blk_begin;        // prefix in fused BLOCK space
};

struct KArgs { Seg seg[14]; int n; };

// ---- shared Phase C: 4 rows x 4 cols register-tiled matvec, W from global --
__device__ __forceinline__ void phaseC(const Seg& sg, int j0, int tid,
                                       const float* xsh) {
  if (tid < 224) {
    const int rg = tid / 28, cq = tid - rg * 28;
    const int cl = (cq < 14) ? cq : cq - 14;
    const float* Wg = (cq < 14) ? sg.Ws : sg.Wn;
    const int c0 = (cl < 13) ? 4 * cl : 0;
    const int c1 = (cl < 12) ? c0 + 2 : c0;
    const int xoff = (cq < 14) ? 0 : 100;
    float acc[4][4];
#pragma unroll
    for (int i = 0; i < 4; ++i) { acc[i][0] = acc[i][1] = acc[i][2] = acc[i][3] = 0.f; }
    const float* xb = &xsh[(rg * 4) * XSTR + xoff];
#pragma unroll 4
    for (int e = 0; e < 100; ++e) {
      const float2 w0 = *(const float2*)&Wg[e * 50 + c0];
      const float2 w1 = *(const float2*)&Wg[e * 50 + c1];
#pragma unroll
      for (int i = 0; i < 4; ++i) {
        const float a = xb[i * XSTR + e];
        acc[i][0] = fmaf(a, w0.x, acc[i][0]);
        acc[i][1] = fmaf(a, w0.y, acc[i][1]);
        acc[i][2] = fmaf(a, w1.x, acc[i][2]);
        acc[i][3] = fmaf(a, w1.y, acc[i][3]);
      }
    }
    if (cl < 13) {
      const int cbase = (cq < 14 ? 0 : 50) + 4 * cl;
      for (int i = 0; i < 4; ++i) {
        const long j = j0 + rg * 4 + i;
        float* op = sg.outp + j * (long)sg.ostride + cbase;
        if (cl < 12) {
          float4 o;
          o.x = fmaxf(acc[i][0], 0.f); o.y = fmaxf(acc[i][1], 0.f);
          o.z = fmaxf(acc[i][2], 0.f); o.w = fmaxf(acc[i][3], 0.f);
          *(float4*)op = o;
        } else {   // cols 48,49 (or 98,99)
          op[0] = fmaxf(acc[i][0], 0.f);
          op[1] = fmaxf(acc[i][1], 0.f);
        }
      }
    }
  }
}

// ---- gather-mode Phase B (compile-time fanout R) ----
template <int R>
__device__ __forceinline__ void phaseB_g(const Seg& sg, int tid, float* xsh,
                                         const int* ids_s_sh, const int* ids_n_sh) {
  const float rinv = 1.f / (float)R;
  for (int u = tid; u < RPB * 25; u += 256) {
    const int row = u / 25, q4 = (u - row * 25) * 4;
    float4 s4 = *(const float4*)(sg.emb + (long)ids_s_sh[row] * sg.estride + q4);
    float mx = 0.f, my = 0.f, mz = 0.f, mw = 0.f;
#pragma unroll
    for (int rr = 0; rr < R; ++rr) {
      const float4 t = *(const float4*)(sg.emb + (long)ids_n_sh[row * R + rr] * sg.estride + q4);
      mx += t.x; my += t.y; mz += t.z; mw += t.w;
    }
    *(float4*)&xsh[row * XSTR + q4] = s4;
    float4 mv; mv.x = mx * rinv; mv.y = my * rinv; mv.z = mz * rinv; mv.w = mw * rinv;
    *(float4*)&xsh[row * XSTR + 100 + q4] = mv;
  }
}

// ---- dense-mode Phase B (compile-time fanout R) ----
template <int R>
__device__ __forceinline__ void phaseB_d(const Seg& sg, int j0, int tid, float* xsh) {
  const float rinv = 1.f / (float)R;
  for (int u = tid; u < RPB * 25; u += 256) {
    const int row = u / 25, q4 = (u - row * 25) * 4;
    const long j = j0 + row;
    float4 s4 = *(const float4*)(sg.selfp + j * 100 + q4);
    float mx = 0.f, my = 0.f, mz = 0.f, mw = 0.f;
#pragma unroll
    for (int rr = 0; rr < R; ++rr) {
      const float4 t = *(const float4*)(sg.neighp + (j * R + rr) * 100 + q4);
      mx += t.x; my += t.y; mz += t.z; mw += t.w;
    }
    *(float4*)&xsh[row * XSTR + q4] = s4;
    float4 mv; mv.x = mx * rinv; mv.y = my * rinv; mv.z = mz * rinv; mv.w = mw * rinv;
    *(float4*)&xsh[row * XSTR + 100 + q4] = mv;
  }
}

__global__ __launch_bounds__(256, 4) void agg_gather(KArgs P) {
  __shared__ float xsh[RPB * XSTR];
  __shared__ int   ids_s_sh[RPB];
  __shared__ int   ids_n_sh[RPB * 9];

  const int blk = blockIdx.x, tid = threadIdx.x;
  int si = 0;
  for (int i = 1; i < P.n; ++i)
    if (blk >= P.seg[i].blk_begin) si = i;
  const Seg sg = P.seg[si];
  const int j0 = (blk - sg.blk_begin) * RPB;
  const int c = sg.c, r = sg.r;

  if (tid < RPB) {
    int j = j0 + tid, b = j / c, pos = j - b * c;
    ids_s_sh[tid] = sg.ids_s[(long)b * sg.ss + sg.so + pos];
  }
  for (int u = tid; u < RPB * r; u += 256) {
    int row = u / r, q = u - row * r;
    int j = j0 + row, b = j / c, pos = j - b * c;
    ids_n_sh[u] = sg.ids_n[(long)b * sg.ns + sg.no + pos * r + q];
  }
  __syncthreads();

  switch (r) {
    case 3: phaseB_g<3>(sg, tid, xsh, ids_s_sh, ids_n_sh); break;
    case 5: phaseB_g<5>(sg, tid, xsh, ids_s_sh, ids_n_sh); break;
    case 7: phaseB_g<7>(sg, tid, xsh, ids_s_sh, ids_n_sh); break;
    default: phaseB_g<9>(sg, tid, xsh, ids_s_sh, ids_n_sh); break;
  }
  __syncthreads();

  phaseC(sg, j0, tid, xsh);
}

__device__ __forceinline__ void agg_dense_body(const KArgs& P) {
  __shared__ float xsh[RPB * XSTR];

  const int blk = blockIdx.x, tid = threadIdx.x;
  int si = 0;
  for (int i = 1; i < P.n; ++i)
    if (blk >= P.seg[i].blk_begin) si = i;
  const Seg sg = P.seg[si];
  const int j0 = (blk - sg.blk_begin) * RPB;

  switch (sg.r) {
    case 3: phaseB_d<3>(sg, j0, tid, xsh); break;
    case 5: phaseB_d<5>(sg, j0, tid, xsh); break;
    default: phaseB_d<7>(sg, j0, tid, xsh); break;
  }
  __syncthreads();

  phaseC(sg, j0, tid, xsh);
}

__global__ __launch_bounds__(256, 4) void agg_dense1(KArgs P) { agg_dense_body(P); }
__global__ __launch_bounds__(256, 4) void agg_dense2(KArgs P) { agg_dense_body(P); }
__global__ __launch_bounds__(256, 4) void agg_dense3(KArgs P) { agg_dense_body(P); }

// ---------------------------------------------------------------------------
// Attention step (UNCHANGED numerics/body from R6). tid is GROUP-LOCAL
// (0..127); barriers sync the whole 384-thread block, so every group must
// execute the same number of __syncthreads — exactly 7 per call (see
// attn_step_noop below; keep them in sync if editing!).
// ---------------------------------------------------------------------------
__device__ __forceinline__ void attn_step(
    float* xs, int base, int rs, int n,
    const float* __restrict__ Wq, const float* __restrict__ Wk,
    const float* __restrict__ Wv, const float* __restrict__ Wf,
    const float* __restrict__ g, const float* __restrict__ bb,
    float* ln, float* qq, float* kk, float* vv, float* ot,
    float* sc, float* musd, int tid)
{
  if (tid < n) {
    float mu = 0.f;
    for (int d = 0; d < 100; ++d) mu += xs[base + tid * rs + d];
    mu *= 0.01f;
    float var = 0.f;
    for (int d = 0; d < 100; ++d) {
      float t = xs[base + tid * rs + d] - mu; var = fmaf(t, t, var);
    }
    var *= 0.01f;
    musd[tid * 2]     = mu;
    musd[tid * 2 + 1] = rsqrtf(var + 1e-6f);
  }
  __syncthreads();                                     // 1
  for (int o = tid; o < n * 100; o += 128) {
    int i = o / 100, d = o - i * 100;
    ln[o] = (xs[base + i * rs + d] - musd[i * 2]) * musd[i * 2 + 1] * g[d] + bb[d];
  }
  __syncthreads();                                     // 2

  // ---- q,k,v: thread owns (row i, 4 cols d4), W direct from global ----
  const bool act = tid < n * 25;
  const int  i   = tid / 25;
  const int  d4  = 4 * (tid - i * 25);
  if (act) {
    float aq[4] = {0,0,0,0}, ak[4] = {0,0,0,0}, av[4] = {0,0,0,0};
#pragma unroll 4
    for (int el = 0; el < 100; ++el) {
      const float lnv = ln[i * 100 + el];
      const float xv  = xs[base + i * rs + el];
      const float4 wq = *(const float4*)&Wq[el * 100 + d4];
      const float4 wk = *(const float4*)&Wk[el * 100 + d4];
      const float4 wv = *(const float4*)&Wv[el * 100 + d4];
      aq[0] = fmaf(lnv, wq.x, aq[0]); aq[1] = fmaf(lnv, wq.y, aq[1]);
      aq[2] = fmaf(lnv, wq.z, aq[2]); aq[3] = fmaf(lnv, wq.w, aq[3]);
      ak[0] = fmaf(xv,  wk.x, ak[0]); ak[1] = fmaf(xv,  wk.y, ak[1]);
      ak[2] = fmaf(xv,  wk.z, ak[2]); ak[3] = fmaf(xv,  wk.w, ak[3]);
      av[0] = fmaf(xv,  wv.x, av[0]); av[1] = fmaf(xv,  wv.y, av[1]);
      av[2] = fmaf(xv,  wv.z, av[2]); av[3] = fmaf(xv,  wv.w, av[3]);
    }
#pragma unroll
    for (int jj = 0; jj < 4; ++jj) {
      qq[i * 100 + d4 + jj] = aq[jj];
      kk[i * 100 + d4 + jj] = ak[jj];
      vv[i * 100 + d4 + jj] = av[jj];
    }
  }
  __syncthreads();                                     // 3

  if (tid < n * n) {
    int qi = tid / n, u = tid - qi * n;
    float s = 0.f;
    for (int d = 0; d < 100; ++d) s = fmaf(qq[qi * 100 + d], kk[u * 100 + d], s);
    sc[tid] = s * 0.1f;
  }
  __syncthreads();                                     // 4
  if (tid < n) {
    float mx = sc[tid * n];
    for (int u = 1; u < n; ++u) mx = fmaxf(mx, sc[tid * n + u]);
    float sm = 0.f;
    for (int u = 0; u < n; ++u) {
      float e = expf(sc[tid * n + u] - mx); sc[tid * n + u] = e; sm += e;
    }
    float inv = 1.f / sm;
    for (int u = 0; u < n; ++u) sc[tid * n + u] *= inv;
  }
  __syncthreads();                                     // 5
  for (int o = tid; o < n * 100; o += 128) {
    int ii = o / 100, d = o - ii * 100;
    float a = 0.f;
    for (int u = 0; u < n; ++u) a = fmaf(sc[ii * n + u], vv[u * 100 + d], a);
    ot[o] = a;
  }
  __syncthreads();                                     // 6

  // ---- Wf + residual, direct from global ----
  if (act) {
    float af[4] = {0,0,0,0};
#pragma unroll 4
    for (int el = 0; el < 100; ++el) {
      const float ov = ot[i * 100 + el];
      const float4 wf = *(const float4*)&Wf[el * 100 + d4];
      af[0] = fmaf(ov, wf.x, af[0]); af[1] = fmaf(ov, wf.y, af[1]);
      af[2] = fmaf(ov, wf.z, af[2]); af[3] = fmaf(ov, wf.w, af[3]);
    }
#pragma unroll
    for (int jj = 0; jj < 4; ++jj)
      xs[base + i * rs + d4 + jj] += af[jj];
  }
  __syncthreads();                                     // 7
}

// barrier-matching no-op: MUST execute exactly as many __syncthreads as
// attn_step (7).
__device__ __forceinline__ void attn_step_noop() {
#pragma unroll
  for (int q = 0; q < 7; ++q) __syncthreads();
}

__global__ __launch_bounds__(384) void attn_final_kernel(
    const float* __restrict__ spec, const float* __restrict__ rview,
    const int* __restrict__ nodeids, const int* __restrict__ edgetype,
    const float* __restrict__ base_embed, const float* __restrict__ reflect,
    const float* __restrict__ vWq, const float* __restrict__ vWk,
    const float* __restrict__ vWv, const float* __restrict__ vWf,
    const float* __restrict__ vg, const float* __restrict__ vb,
    const float* __restrict__ mWq, const float* __restrict__ mWk,
    const float* __restrict__ mWv, const float* __restrict__ mWf,
    const float* __restrict__ mg, const float* __restrict__ mb,
    float* __restrict__ out)
{
  __shared__ float xs[600];
  __shared__ float lnB[3][300], qqB[3][300], kkB[3][300], vvB[3][300], otB[3][300];
  __shared__ float scB[3][12], musdB[3][8];
  __shared__ float r200[200], pooled[200], nrmv[1];
  const int b = blockIdx.x, tid = threadIdx.x;
  const int g = tid >> 7, gt = tid & 127;   // group 0..2, group-local tid

  for (int o = tid; o < 600; o += 384) {
    int v = o / 200, rem = o - v * 200;
    xs[o] = (v < 2) ? spec[(long)b * 400 + o] : rview[(long)b * 100 + (rem % 100)];
  }
  __syncthreads();

  // ---- view attention: 3 independent steps run concurrently (1 per group).
  // Group v owns xs[v*200 : (v+1)*200] — disjoint slices, no races.
  attn_step(xs, g * 200, 100, 2, vWq, vWk, vWv, vWf, vg, vb,
            lnB[g], qqB[g], kkB[g], vvB[g], otB[g], scB[g], musdB[g], gt);

  // ---- meta attention: 2 independent steps (t=0,1) run concurrently.
  // Group t touches xs[t*100 + i*200 + d] — disjoint for t=0/1.
  if (g < 2)
    attn_step(xs, g * 100, 200, 3, mWq, mWk, mWv, mWf, mg, mb,
              lnB[g], qqB[g], kkB[g], vvB[g], otB[g], scB[g], musdB[g], gt);
  else
    attn_step_noop();

  for (int o = tid; o < 200; o += 384)
    pooled[o] = (xs[o] + xs[200 + o] + xs[400 + o]) * (1.f / 3.f);
  __syncthreads();

  const int  et  = edgetype[NBATCH + b];
  const long nid = nodeids[b];

  float ar[4] = {0,0,0,0};
  if (tid < 50) {
    const float4 be = *(const float4*)&base_embed[nid * 200 + 4 * tid];
    ar[0] = be.x; ar[1] = be.y; ar[2] = be.z; ar[3] = be.w;
#pragma unroll 4
    for (int dl = 0; dl < 100; ++dl) {
      const float pv = pooled[et * 100 + dl];
      const float4 rv = *(const float4*)&reflect[((long)et * 100 + dl) * 200 + 4 * tid];
      ar[0] = fmaf(pv, rv.x, ar[0]); ar[1] = fmaf(pv, rv.y, ar[1]);
      ar[2] = fmaf(pv, rv.z, ar[2]); ar[3] = fmaf(pv, rv.w, ar[3]);
    }
    r200[4 * tid]     = ar[0]; r200[4 * tid + 1] = ar[1];
    r200[4 * tid + 2] = ar[2]; r200[4 * tid + 3] = ar[3];
  }
  __syncthreads();
  if (tid == 0) {
    float ss = 0.f;
    for (int o = 0; o < 200; ++o) ss = fmaf(r200[o], r200[o], ss);
    nrmv[0] = 1.f / fmaxf(sqrtf(ss), 1e-12f);
  }
  __syncthreads();
  for (int o = tid; o < 200; o += 384)
    out[(long)b * 200 + o] = r200[o] * nrmv[0];
}

// ---------------------------------------------------------------------------
extern "C" void kernel_launch(void* const* d_in, const int* in_sizes, int n_in,
                              void* d_out, int out_size, void* d_ws, size_t ws_size,
                              hipStream_t stream) {
  (void)in_sizes; (void)n_in; (void)out_size; (void)ws_size;
  const int*   nodeids          = (const int*)d_in[0];
  const int*   edgetype         = (const int*)d_in[1];
  const int*   neighbors        = (const int*)d_in[2];
  const int*   random_neighbors = (const int*)d_in[3];
  const float* base_embed       = (const float*)d_in[4];
  const float* type_embed       = (const float*)d_in[5];
  const float* rw_embed         = (const float*)d_in[6];
  const float* reflect          = (const float*)d_in[7];
  const float* agg0_self        = (const float*)d_in[8];
  const float* agg0_neigh       = (const float*)d_in[9];
  const float* agg1_self        = (const float*)d_in[10];
  const float* agg1_neigh       = (const float*)d_in[11];
  const float* rand_self        = (const float*)d_in[12];
  const float* rand_neigh       = (const float*)d_in[13];
  const float* vWq = (const float*)d_in[14];
  const float* vWk = (const float*)d_in[15];
  const float* vWv = (const float*)d_in[16];
  const float* vWf = (const float*)d_in[17];
  const float* vg  = (const float*)d_in[18];
  const float* vb  = (const float*)d_in[19];
  const float* mWq = (const float*)d_in[20];
  const float* mWk = (const float*)d_in[21];
  const float* mWv = (const float*)d_in[22];
  const float* mWf = (const float*)d_in[23];
  const float* mg  = (const float*)d_in[24];
  const float* mb  = (const float*)d_in[25];

  float* ws = (float*)d_ws;
  const long S1r = 147L * NBATCH;                 // schema1 rows per t
  auto rp = [&](long rows) { return ws + rows * 100; };
  float* spec_f  = ws + 306L * NBATCH * 100;      // [B][2][2][100]
  float* rview_f = spec_f + (long)NBATCH * 400;   // [B][100]

  const int  OFF1[4] = {18, 21, 36, 141};
  const int  FAN1[4] = {3, 5, 7, 9};
  const int  C1[4]   = {1, 3, 15, 105};
  const long CUM1[4]  = {0, 1, 4, 19};
  const long CUM1b[3] = {0, 1, 4};

  KArgs A; long acc = 0;   // acc in BLOCKS (32 rows each)
  auto addg = [&](const float* emb, int estride,
                  const int* isrc, int ss, int so, int c,
                  const int* insrc, int nstr, int no, int r,
                  const float* Ws, const float* Wn, float* outp, int ostride) {
    Seg& s = A.seg[A.n++];
    s.emb = emb; s.selfp = nullptr; s.neighp = nullptr;
    s.ids_s = isrc; s.ids_n = insrc;
    s.Ws = Ws; s.Wn = Wn; s.outp = outp;
    s.ss = ss; s.so = so; s.ns = nstr; s.no = no;
    s.estride = estride; s.ostride = ostride;
    s.c = c; s.r = r; s.blk_begin = (int)acc;
    acc += (long)c * NBATCH / RPB;
  };
  auto addd = [&](const float* selfp, const float* neighp, int c, int r,
                  const float* Ws, const float* Wn, float* outp, int ostride) {
    Seg& s = A.seg[A.n++];
    s.emb = nullptr; s.selfp = selfp; s.neighp = neighp;
    s.ids_s = nullptr; s.ids_n = nullptr;
    s.Ws = Ws; s.Wn = Wn; s.outp = outp;
    s.ss = 0; s.so = 0; s.ns = 0; s.no = 0; s.estride = 0; s.ostride = ostride;
    s.c = c; s.r = r; s.blk_begin = (int)acc;
    acc += (long)c * NBATCH / RPB;
  };

  // ---- launch 0: all level-0 (gather) pairs ----
  A.n = 0; acc = 0;
  for (int t = 0; t < 2; ++t)
    for (int k = 0; k < 4; ++k) {
      const float* emb = type_embed + (t * 2 + 1) * 100;
      if (k == 0)
        addg(emb, 400, nodeids, 1, 0, 1,
             neighbors, 2 * TOTALP, t * TOTALP + OFF1[k], FAN1[k],
             agg1_self, agg1_neigh, rp(t * S1r + CUM1[k] * NBATCH), 100);
      else
        addg(emb, 400, neighbors, 2 * TOTALP, t * TOTALP + OFF1[k - 1], C1[k],
             neighbors, 2 * TOTALP, t * TOTALP + OFF1[k], FAN1[k],
             agg1_self, agg1_neigh, rp(t * S1r + CUM1[k] * NBATCH), 100);
    }
  for (int t = 0; t < 2; ++t)
    for (int k = 0; k < 2; ++k) {
      const float* emb = type_embed + (t * 2 + 0) * 100;
      long obase = 294L * NBATCH + (long)t * 4 * NBATCH + (k == 0 ? 0 : 1) * NBATCH;
      if (k == 0)
        addg(emb, 400, nodeids, 1, 0, 1,
             neighbors, 2 * TOTALP, t * TOTALP + 0, 3,
             agg0_self, agg0_neigh, rp(obase), 100);
      else
        addg(emb, 400, neighbors, 2 * TOTALP, t * TOTALP + 0, 3,
             neighbors, 2 * TOTALP, t * TOTALP + 3, 5,
             agg0_self, agg0_neigh, rp(obase), 100);
    }
  for (int k = 0; k < 2; ++k) {
    long obase = 302L * NBATCH + (k == 0 ? 0 : 1) * NBATCH;
    if (k == 0)
      addg(rw_embed, 100, nodeids, 1, 0, 1,
           random_neighbors, 18, 0, 3, rand_self, rand_neigh, rp(obase), 100);
    else
      addg(rw_embed, 100, random_neighbors, 18, 0, 3,
           random_neighbors, 18, 3, 5, rand_self, rand_neigh, rp(obase), 100);
  }
  agg_gather<<<dim3((unsigned)acc), dim3(256), 0, stream>>>(A);

  // ---- launch 1: schema1 L1, schema0 L1 (final), random L1 (final) ----
  A.n = 0; acc = 0;
  for (int t = 0; t < 2; ++t)
    for (int k = 0; k < 3; ++k)
      addd(rp(t * S1r + CUM1[k] * NBATCH), rp(t * S1r + CUM1[k + 1] * NBATCH),
           C1[k], FAN1[k], agg1_self + 5000, agg1_neigh + 5000,
           rp(t * S1r + 124L * NBATCH + CUM1b[k] * NBATCH), 100);
  for (int t = 0; t < 2; ++t)
    addd(rp(294L * NBATCH + (long)t * 4 * NBATCH),
         rp(294L * NBATCH + (long)t * 4 * NBATCH + NBATCH),
         1, 3, agg0_self + 5000, agg0_neigh + 5000, spec_f + t * 100, 400);
  addd(rp(302L * NBATCH), rp(303L * NBATCH), 1, 3,
       rand_self + 5000, rand_neigh + 5000, rview_f, 100);
  agg_dense1<<<dim3((unsigned)acc), dim3(256), 0, stream>>>(A);

  // ---- launch 2: schema1 L2 ----
  A.n = 0; acc = 0;
  for (int t = 0; t < 2; ++t)
    for (int k = 0; k < 2; ++k)
      addd(rp(t * S1r + 124L * NBATCH + CUM1b[k] * NBATCH),
           rp(t * S1r + 124L * NBATCH + CUM1b[k + 1] * NBATCH),
           C1[k], FAN1[k], agg1_self + 10000, agg1_neigh + 10000,
           rp(t * S1r + 143L * NBATCH + (k == 0 ? 0 : 1) * NBATCH), 100);
  agg_dense2<<<dim3((unsigned)acc), dim3(256), 0, stream>>>(A);

  // ---- launch 3: schema1 L3 (final -> spec view 1) ----
  A.n = 0; acc = 0;
  for (int t = 0; t < 2; ++t)
    addd(rp(t * S1r + 143L * NBATCH), rp(t * S1r + 144L * NBATCH),
         1, 3, agg1_self + 15000, agg1_neigh + 15000,
         spec_f + 200 + t * 100, 400);
  agg_dense3<<<dim3((unsigned)acc), dim3(256), 0, stream>>>(A);

  // ---- launch 4: attention + epilogue ----
  attn_final_kernel<<<dim3(NBATCH), dim3(384), 0, stream>>>(
      spec_f, rview_f, nodeids, edgetype, base_embed, reflect,
      vWq, vWk, vWv, vWf, vg, vb, mWq, mWk, mWv, mWf, mg, mb,
      (float*)d_out);
}